// Round 1
// baseline (1252.945 us; speedup 1.0000x reference)
//
#include <hip/hip_runtime.h>
#include <hip/hip_bf16.h>
#include <stdint.h>

// Problem constants
#define A_N 8
#define B_N 32768
#define IN_N 128
#define OUT_N 32
#define SAF 160      // IN + OUT
#define H_N 128
#define D_N 32
#define KD_N 128     // K*D
#define CIN_N 256    // critic input = H + K*D
#define CHUNKS 128   // stats chunks over B
#define EPSV 1e-5f

typedef unsigned int u32;
typedef unsigned short u16;

__device__ __forceinline__ float bf_lo(u32 u){ return __uint_as_float(u << 16); }
__device__ __forceinline__ float bf_hi(u32 u){ return __uint_as_float(u & 0xffff0000u); }
__device__ __forceinline__ float bf2f(u16 b){ return __uint_as_float(((u32)b) << 16); }
__device__ __forceinline__ u16 f2bf(float f){
  u32 u = __float_as_uint(f);
  return (u16)((u + 0x7fffu + ((u >> 16) & 1u)) >> 16);
}
__device__ __forceinline__ float lrelu(float x){ return x > 0.f ? x : 0.01f * x; }

// ---------------------------------------------------------------------------
// Stage 1: BN statistics (sum, sumsq) per (agent, feature). Deterministic
// two-phase: per-chunk partials -> finalize. Features 0..127 = states,
// 128..159 = actions (concat-BN per-feature stats == per-array stats).
// ---------------------------------------------------------------------------
__global__ __launch_bounds__(256) void k_stats(
    const float* __restrict__ states, const float* __restrict__ actions,
    float* __restrict__ part)
{
  int a = blockIdx.y;
  int chunk = blockIdx.x;
  int t = threadIdx.x;
  int r0 = chunk * (B_N / CHUNKS);   // 256 rows per chunk
  __shared__ float red[512];
  // states part: f = t&127, half = t>>7 (2 rows/pass, 128 passes)
  {
    int f = t & 127, half = t >> 7;
    const float* p = states + ((size_t)a * B_N + r0 + half) * IN_N + f;
    float s1 = 0.f, s2 = 0.f;
    for (int it = 0; it < 128; ++it){
      float v = p[(size_t)(2 * it) * IN_N];
      s1 += v; s2 += v * v;
    }
    red[t] = s1; red[256 + t] = s2;
    __syncthreads();
    if (t < 128){
      float a1 = red[t] + red[t + 128];
      float a2 = red[256 + t] + red[256 + t + 128];
      size_t o = (((size_t)a * CHUNKS + chunk) * SAF + t) * 2;
      part[o] = a1; part[o + 1] = a2;
    }
    __syncthreads();
  }
  // actions part: f = t&31, g = t>>5 (8 rows/pass, 32 passes)
  {
    int f = t & 31, g = t >> 5;
    const float* p = actions + ((size_t)a * B_N + r0 + g) * OUT_N + f;
    float s1 = 0.f, s2 = 0.f;
    for (int it = 0; it < 32; ++it){
      float v = p[(size_t)(8 * it) * OUT_N];
      s1 += v; s2 += v * v;
    }
    red[t] = s1; red[256 + t] = s2;
    __syncthreads();
    if (t < 32){
      float a1 = 0.f, a2 = 0.f;
      #pragma unroll
      for (int gg = 0; gg < 8; ++gg){
        a1 += red[t + 32 * gg];
        a2 += red[256 + t + 32 * gg];
      }
      size_t o = (((size_t)a * CHUNKS + chunk) * SAF + 128 + t) * 2;
      part[o] = a1; part[o + 1] = a2;
    }
  }
}

__global__ void k_finalize(const float* __restrict__ part,
                           float* __restrict__ meanArr, float* __restrict__ istdArr)
{
  int idx = blockIdx.x * blockDim.x + threadIdx.x;
  if (idx >= A_N * SAF) return;
  int a = idx / SAF, f = idx % SAF;
  float s1 = 0.f, s2 = 0.f;
  for (int c = 0; c < CHUNKS; ++c){
    size_t o = (((size_t)a * CHUNKS + c) * SAF + f) * 2;
    s1 += part[o]; s2 += part[o + 1];
  }
  float m = s1 * (1.f / B_N);
  float v = s2 * (1.f / B_N) - m * m;
  if (v < 0.f) v = 0.f;
  meanArr[idx] = m;
  istdArr[idx] = rsqrtf(v + EPSV);
}

// ---------------------------------------------------------------------------
// Shared GEMM inner loop: 64x128 output tile, BK=32, thread = 4 rows x 8 cols
// ---------------------------------------------------------------------------
__device__ __forceinline__ void mac_tile(float (*Xs)[68], float (*Ws)[128],
                                         int tx, int ty, float acc[4][8])
{
  #pragma unroll 8
  for (int kk = 0; kk < 32; ++kk){
    float4 xv = *(const float4*)&Xs[kk][ty * 4];
    float4 wa = *(const float4*)&Ws[kk][tx * 8];
    float4 wb = *(const float4*)&Ws[kk][tx * 8 + 4];
    float xr[4] = {xv.x, xv.y, xv.z, xv.w};
    float wr[8] = {wa.x, wa.y, wa.z, wa.w, wb.x, wb.y, wb.z, wb.w};
    #pragma unroll
    for (int i = 0; i < 4; ++i)
      #pragma unroll
      for (int j = 0; j < 8; ++j)
        acc[i][j] = fmaf(xr[i], wr[j], acc[i][j]);
  }
}

// ---------------------------------------------------------------------------
// Stage 2: sa_enc = lrelu(BN(concat(states,actions)) @ enc_w + enc_b) -> bf16
// ---------------------------------------------------------------------------
__global__ __launch_bounds__(256) void k_enc(
    const float* __restrict__ states, const float* __restrict__ actions,
    const float* __restrict__ meanArr, const float* __restrict__ istdArr,
    const float* __restrict__ enc_w, const float* __restrict__ enc_b,
    u16* __restrict__ out)
{
  int a = blockIdx.y;
  int row0 = blockIdx.x * 64;
  int t = threadIdx.x, tx = t & 15, ty = t >> 4;
  __shared__ float Xs[32][68];
  __shared__ float Ws[32][128];
  float acc[4][8];
  #pragma unroll
  for (int i = 0; i < 4; ++i)
    #pragma unroll
    for (int j = 0; j < 8; ++j) acc[i][j] = 0.f;
  const float* wbase = enc_w + (size_t)a * SAF * H_N;
  int kp = (t & 15) * 2, rr = t >> 4;
  for (int k0 = 0; k0 < SAF; k0 += 32){
    int f0 = k0 + kp;
    float m0 = meanArr[a * SAF + f0],     s0 = istdArr[a * SAF + f0];
    float m1 = meanArr[a * SAF + f0 + 1], s1 = istdArr[a * SAF + f0 + 1];
    #pragma unroll
    for (int rp = 0; rp < 4; ++rp){
      int r = rr + rp * 16;
      size_t row = (size_t)a * B_N + row0 + r;
      float v0, v1;
      if (f0 < IN_N){
        const float* p = states + row * IN_N + f0;
        v0 = p[0]; v1 = p[1];
      } else {
        const float* p = actions + row * OUT_N + (f0 - IN_N);
        v0 = p[0]; v1 = p[1];
      }
      Xs[kp][r]     = (v0 - m0) * s0;
      Xs[kp + 1][r] = (v1 - m1) * s1;
    }
    #pragma unroll
    for (int p4 = 0; p4 < 4; ++p4){
      int e = t + p4 * 256;
      int kk = e >> 5, n4 = (e & 31) * 4;
      *(float4*)&Ws[kk][n4] = *(const float4*)(wbase + (size_t)(k0 + kk) * H_N + n4);
    }
    __syncthreads();
    mac_tile(Xs, Ws, tx, ty, acc);
    __syncthreads();
  }
  #pragma unroll
  for (int i = 0; i < 4; ++i){
    int row = row0 + ty * 4 + i;
    __align__(16) u16 pk[8];
    #pragma unroll
    for (int j = 0; j < 8; ++j){
      int col = tx * 8 + j;
      pk[j] = f2bf(lrelu(acc[i][j] + enc_b[a * H_N + col]));
    }
    *(uint4*)(out + ((size_t)a * B_N + row) * H_N + tx * 8) = *(const uint4*)pk;
  }
}

// ---------------------------------------------------------------------------
// Stage 3: a_enc = lrelu(BN(actions) @ aenc_w + aenc_b) -> bf16  (K = 32)
// ---------------------------------------------------------------------------
__global__ __launch_bounds__(256) void k_aenc(
    const float* __restrict__ actions,
    const float* __restrict__ meanArr, const float* __restrict__ istdArr,
    const float* __restrict__ aenc_w, const float* __restrict__ aenc_b,
    u16* __restrict__ out)
{
  int a = blockIdx.y;
  int row0 = blockIdx.x * 64;
  int t = threadIdx.x, tx = t & 15, ty = t >> 4;
  __shared__ float Xs[32][68];
  __shared__ float Ws[32][128];
  float acc[4][8];
  #pragma unroll
  for (int i = 0; i < 4; ++i)
    #pragma unroll
    for (int j = 0; j < 8; ++j) acc[i][j] = 0.f;
  const float* wbase = aenc_w + (size_t)a * OUT_N * H_N;
  int kp = (t & 15) * 2, rr = t >> 4;
  {
    int f0 = kp;  // 0..30 within actions
    float m0 = meanArr[a * SAF + 128 + f0],     s0 = istdArr[a * SAF + 128 + f0];
    float m1 = meanArr[a * SAF + 128 + f0 + 1], s1 = istdArr[a * SAF + 128 + f0 + 1];
    #pragma unroll
    for (int rp = 0; rp < 4; ++rp){
      int r = rr + rp * 16;
      size_t row = (size_t)a * B_N + row0 + r;
      const float* p = actions + row * OUT_N + f0;
      Xs[kp][r]     = (p[0] - m0) * s0;
      Xs[kp + 1][r] = (p[1] - m1) * s1;
    }
    #pragma unroll
    for (int p4 = 0; p4 < 4; ++p4){
      int e = t + p4 * 256;
      int kk = e >> 5, n4 = (e & 31) * 4;
      *(float4*)&Ws[kk][n4] = *(const float4*)(wbase + (size_t)kk * H_N + n4);
    }
    __syncthreads();
    mac_tile(Xs, Ws, tx, ty, acc);
    __syncthreads();
  }
  #pragma unroll
  for (int i = 0; i < 4; ++i){
    int row = row0 + ty * 4 + i;
    __align__(16) u16 pk[8];
    #pragma unroll
    for (int j = 0; j < 8; ++j){
      int col = tx * 8 + j;
      pk[j] = f2bf(lrelu(acc[i][j] + aenc_b[a * H_N + col]));
    }
    *(uint4*)(out + ((size_t)a * B_N + row) * H_N + tx * 8) = *(const uint4*)pk;
  }
}

// ---------------------------------------------------------------------------
// Stage 4: Y = [lrelu](X @ W3 [+ bias]); X bf16 [A][B][128];
// W3 is [K,H,D] repacked on the fly to [H][K*D]. Output bf16 [A][B][K*D].
// ---------------------------------------------------------------------------
__global__ __launch_bounds__(256) void k_h128(
    const u16* __restrict__ xin, const float* __restrict__ w3,
    const float* __restrict__ bias, u16* __restrict__ out, int doAct)
{
  int a = blockIdx.y;
  int row0 = blockIdx.x * 64;
  int t = threadIdx.x, tx = t & 15, ty = t >> 4;
  __shared__ float Xs[32][68];
  __shared__ float Ws[32][128];
  float acc[4][8];
  #pragma unroll
  for (int i = 0; i < 4; ++i)
    #pragma unroll
    for (int j = 0; j < 8; ++j) acc[i][j] = 0.f;
  int kp = (t & 15) * 2, rr = t >> 4;
  for (int k0 = 0; k0 < H_N; k0 += 32){
    #pragma unroll
    for (int rp = 0; rp < 4; ++rp){
      int r = rr + rp * 16;
      u32 u = *(const u32*)(xin + ((size_t)a * B_N + row0 + r) * H_N + k0 + kp);
      Xs[kp][r]     = bf_lo(u);
      Xs[kp + 1][r] = bf_hi(u);
    }
    #pragma unroll
    for (int p = 0; p < 16; ++p){
      int e = t + p * 256;
      int kk = e >> 7, n = e & 127;
      Ws[kk][n] = w3[(((size_t)(n >> 5)) * H_N + (k0 + kk)) * D_N + (n & 31)];
    }
    __syncthreads();
    mac_tile(Xs, Ws, tx, ty, acc);
    __syncthreads();
  }
  #pragma unroll
  for (int i = 0; i < 4; ++i){
    int row = row0 + ty * 4 + i;
    __align__(16) u16 pk[8];
    #pragma unroll
    for (int j = 0; j < 8; ++j){
      int col = tx * 8 + j;
      float y = acc[i][j];
      if (doAct) y = lrelu(y + bias[col]);   // val_b[k][d] flattens to [col]
      pk[j] = f2bf(y);
    }
    *(uint4*)(out + ((size_t)a * B_N + row) * H_N + tx * 8) = *(const uint4*)pk;
  }
}

// ---------------------------------------------------------------------------
// Stage 5: attention. Block = 8 b-rows, all agents/heads in LDS.
// other[i][b][k*32+d] = sum_j softmax_j(sel_i . key_j / sqrt(D), j != i) * val_j
// ---------------------------------------------------------------------------
__global__ __launch_bounds__(256) void k_attn(
    const u16* __restrict__ sels, const u16* __restrict__ keys,
    const u16* __restrict__ vals, u16* __restrict__ other)
{
  int b0 = blockIdx.x * 8;
  int t = threadIdx.x;
  __shared__ u16 sS[8192], sK[8192], sV[8192];   // [agent][b_local][k*32+d]
  u32* dS = (u32*)sS; u32* dK = (u32*)sK; u32* dV = (u32*)sV;
  #pragma unroll
  for (int a = 0; a < 8; ++a){
    size_t go = ((size_t)a * B_N + b0) * KD_N;
    const u32* gs = (const u32*)(sels + go);
    const u32* gk = (const u32*)(keys + go);
    const u32* gv = (const u32*)(vals + go);
    dS[a * 512 + t] = gs[t]; dS[a * 512 + 256 + t] = gs[256 + t];
    dK[a * 512 + t] = gk[t]; dK[a * 512 + 256 + t] = gk[256 + t];
    dV[a * 512 + t] = gv[t]; dV[a * 512 + 256 + t] = gv[256 + t];
  }
  __syncthreads();
  int i = t & 7, p = t >> 3;
  int k = p & 3, bl = p >> 2;
  int base_i = (i * 8 + bl) * 128 + k * 32;
  float si[32];
  {
    const u32* S32 = (const u32*)&sS[base_i];
    #pragma unroll
    for (int d2 = 0; d2 < 16; ++d2){
      u32 u = S32[d2];
      si[2 * d2] = bf_lo(u); si[2 * d2 + 1] = bf_hi(u);
    }
  }
  float lg[8];
  #pragma unroll
  for (int j = 0; j < 8; ++j){
    const u32* K32 = (const u32*)&sK[(j * 8 + bl) * 128 + k * 32];
    float acc = 0.f;
    #pragma unroll
    for (int d2 = 0; d2 < 16; ++d2){
      u32 u = K32[d2];
      acc = fmaf(si[2 * d2], bf_lo(u), acc);
      acc = fmaf(si[2 * d2 + 1], bf_hi(u), acc);
    }
    lg[j] = acc * 0.17677669529663689f;   // 1/sqrt(32)
  }
  float mx = -3.0e38f;
  #pragma unroll
  for (int j = 0; j < 8; ++j) if (j != i) mx = fmaxf(mx, lg[j]);
  float pe[8], se = 0.f;
  #pragma unroll
  for (int j = 0; j < 8; ++j){
    pe[j] = (j == i) ? 0.f : __expf(lg[j] - mx);
    se += pe[j];
  }
  float inv = 1.f / se;
  #pragma unroll
  for (int j = 0; j < 8; ++j) pe[j] *= inv;
  __align__(16) u16 ob[32];
  #pragma unroll
  for (int d2 = 0; d2 < 16; ++d2){
    float acc0 = 0.f, acc1 = 0.f;
    #pragma unroll
    for (int j = 0; j < 8; ++j){
      u32 u = *(const u32*)&sV[(j * 8 + bl) * 128 + k * 32 + 2 * d2];
      acc0 = fmaf(pe[j], bf_lo(u), acc0);
      acc1 = fmaf(pe[j], bf_hi(u), acc1);
    }
    ob[2 * d2] = f2bf(acc0); ob[2 * d2 + 1] = f2bf(acc1);
  }
  uint4* dst = (uint4*)(other + ((size_t)i * B_N + (b0 + bl)) * KD_N + k * 32);
  const uint4* s4 = (const uint4*)ob;
  #pragma unroll
  for (int c = 0; c < 4; ++c) dst[c] = s4[c];
}

// ---------------------------------------------------------------------------
// Stage 6: critic. h = lrelu([sa_enc|other] @ c1_w + c1_b); q = h . c2_w + c2_b
// ---------------------------------------------------------------------------
__global__ __launch_bounds__(256) void k_critic(
    const u16* __restrict__ sa_enc, const u16* __restrict__ other,
    const float* __restrict__ c1_w, const float* __restrict__ c1_b,
    const float* __restrict__ c2_w, const float* __restrict__ c2_b,
    float* __restrict__ qout)
{
  int a = blockIdx.y;
  int row0 = blockIdx.x * 64;
  int t = threadIdx.x, tx = t & 15, ty = t >> 4;
  __shared__ float Xs[32][68];
  __shared__ float Ws[32][128];
  __shared__ float part[64][16];
  float acc[4][8];
  #pragma unroll
  for (int i = 0; i < 4; ++i)
    #pragma unroll
    for (int j = 0; j < 8; ++j) acc[i][j] = 0.f;
  const float* wbase = c1_w + (size_t)a * CIN_N * H_N;
  float c2r[8];
  #pragma unroll
  for (int j = 0; j < 8; ++j) c2r[j] = c2_w[a * H_N + tx * 8 + j];
  int kp = (t & 15) * 2, rr = t >> 4;
  for (int k0 = 0; k0 < CIN_N; k0 += 32){
    int f0 = k0 + kp;
    const u16* src = (f0 < H_N) ? sa_enc : other;
    int fo = (f0 < H_N) ? f0 : (f0 - H_N);
    #pragma unroll
    for (int rp = 0; rp < 4; ++rp){
      int r = rr + rp * 16;
      u32 u = *(const u32*)(src + ((size_t)a * B_N + row0 + r) * H_N + fo);
      Xs[kp][r]     = bf_lo(u);
      Xs[kp + 1][r] = bf_hi(u);
    }
    #pragma unroll
    for (int p4 = 0; p4 < 4; ++p4){
      int e = t + p4 * 256;
      int kk = e >> 5, n4 = (e & 31) * 4;
      *(float4*)&Ws[kk][n4] = *(const float4*)(wbase + (size_t)(k0 + kk) * H_N + n4);
    }
    __syncthreads();
    mac_tile(Xs, Ws, tx, ty, acc);
    __syncthreads();
  }
  #pragma unroll
  for (int i = 0; i < 4; ++i){
    float ps = 0.f;
    #pragma unroll
    for (int j = 0; j < 8; ++j){
      int col = tx * 8 + j;
      float h = lrelu(acc[i][j] + c1_b[a * H_N + col]);
      ps = fmaf(h, c2r[j], ps);
    }
    part[ty * 4 + i][tx] = ps;
  }
  __syncthreads();
  if (t < 64){
    float s = c2_b[a];
    #pragma unroll
    for (int x = 0; x < 16; ++x) s += part[t][x];
    qout[(size_t)a * B_N + row0 + t] = s;
  }
}

// ---------------------------------------------------------------------------
extern "C" void kernel_launch(void* const* d_in, const int* in_sizes, int n_in,
                              void* d_out, int out_size, void* d_ws, size_t ws_size,
                              hipStream_t stream)
{
  const float* states  = (const float*)d_in[0];
  const float* actions = (const float*)d_in[1];
  const float* enc_w   = (const float*)d_in[2];
  const float* enc_b   = (const float*)d_in[3];
  const float* aenc_w  = (const float*)d_in[4];
  const float* aenc_b  = (const float*)d_in[5];
  const float* key_w   = (const float*)d_in[6];
  const float* sel_w   = (const float*)d_in[7];
  const float* val_w   = (const float*)d_in[8];
  const float* val_b   = (const float*)d_in[9];
  const float* c1_w    = (const float*)d_in[10];
  const float* c1_b    = (const float*)d_in[11];
  const float* c2_w    = (const float*)d_in[12];
  const float* c2_b    = (const float*)d_in[13];
  float* q = (float*)d_out;

  // ws layout (needs ~322 MB):
  //   [0, 1310720)          stats partials  (A*CHUNKS*SAF*2 f32)
  //   [1310720, 1315840)    mean  (A*SAF f32)
  //   [1315840, 1320960)    istd  (A*SAF f32)
  //   [2097152, +5*64MB)    bf16 buffers: sa_enc, buf2(a_enc/other), keys, vals, sels
  char* ws = (char*)d_ws;
  float* part    = (float*)ws;
  float* meanArr = (float*)(ws + 1310720);
  float* istdArr = (float*)(ws + 1315840);
  const size_t ibase = 2097152;
  const size_t BUF = (size_t)A_N * B_N * 128 * 2;   // 67,108,864 bytes
  u16* sa_enc = (u16*)(ws + ibase);
  u16* buf2   = (u16*)(ws + ibase + BUF);           // a_enc, later reused as `other`
  u16* keys   = (u16*)(ws + ibase + 2 * BUF);
  u16* vals   = (u16*)(ws + ibase + 3 * BUF);
  u16* sels   = (u16*)(ws + ibase + 4 * BUF);

  k_stats<<<dim3(CHUNKS, A_N), 256, 0, stream>>>(states, actions, part);
  k_finalize<<<(A_N * SAF + 255) / 256, 256, 0, stream>>>(part, meanArr, istdArr);
  k_enc<<<dim3(B_N / 64, A_N), 256, 0, stream>>>(states, actions, meanArr, istdArr,
                                                 enc_w, enc_b, sa_enc);
  k_aenc<<<dim3(B_N / 64, A_N), 256, 0, stream>>>(actions, meanArr, istdArr,
                                                  aenc_w, aenc_b, buf2);
  k_h128<<<dim3(B_N / 64, A_N), 256, 0, stream>>>(buf2, key_w, nullptr, keys, 0);
  k_h128<<<dim3(B_N / 64, A_N), 256, 0, stream>>>(buf2, val_w, val_b, vals, 1);
  k_h128<<<dim3(B_N / 64, A_N), 256, 0, stream>>>(sa_enc, sel_w, nullptr, sels, 0);
  k_attn<<<B_N / 8, 256, 0, stream>>>(sels, keys, vals, buf2);
  k_critic<<<dim3(B_N / 64, A_N), 256, 0, stream>>>(sa_enc, buf2, c1_w, c1_b,
                                                    c2_w, c2_b, q);
}

// Round 3
// 670.757 us; speedup vs baseline: 1.8680x; 1.8680x over previous
//
#include <hip/hip_runtime.h>
#include <hip/hip_bf16.h>
#include <stdint.h>

// Problem constants
#define A_N 8
#define B_N 32768
#define IN_N 128
#define OUT_N 32
#define SAF 160      // IN + OUT
#define H_N 128
#define D_N 32
#define KD_N 128     // K*D
#define CIN_N 256    // critic input = H + K*D
#define CHUNKS 128   // stats chunks over B
#define EPSV 1e-5f
#define ENC_KP 192   // enc K padded 160 -> 192

typedef unsigned int u32;
typedef unsigned short u16;
typedef __attribute__((ext_vector_type(8))) short short8;    // 8 bf16 (4 VGPRs)
typedef __attribute__((ext_vector_type(4))) float floatx4;   // MFMA C/D

__device__ __forceinline__ float bf_lo(u32 u){ return __uint_as_float(u << 16); }
__device__ __forceinline__ float bf_hi(u32 u){ return __uint_as_float(u & 0xffff0000u); }
__device__ __forceinline__ float bf2f(u16 b){ return __uint_as_float(((u32)b) << 16); }
__device__ __forceinline__ u16 f2bf(float f){
  u32 u = __float_as_uint(f);
  return (u16)((u + 0x7fffu + ((u >> 16) & 1u)) >> 16);
}
__device__ __forceinline__ float lrelu(float x){ return x > 0.f ? x : 0.01f * x; }

// ---------------------------------------------------------------------------
// Stage 1: BN statistics (sum, sumsq) per (agent, feature).
// ---------------------------------------------------------------------------
__global__ __launch_bounds__(256) void k_stats(
    const float* __restrict__ states, const float* __restrict__ actions,
    float* __restrict__ part)
{
  int a = blockIdx.y;
  int chunk = blockIdx.x;
  int t = threadIdx.x;
  int r0 = chunk * (B_N / CHUNKS);   // 256 rows per chunk
  __shared__ float red[512];
  {
    int f = t & 127, half = t >> 7;
    const float* p = states + ((size_t)a * B_N + r0 + half) * IN_N + f;
    float s1 = 0.f, s2 = 0.f;
    for (int it = 0; it < 128; ++it){
      float v = p[(size_t)(2 * it) * IN_N];
      s1 += v; s2 += v * v;
    }
    red[t] = s1; red[256 + t] = s2;
    __syncthreads();
    if (t < 128){
      float a1 = red[t] + red[t + 128];
      float a2 = red[256 + t] + red[256 + t + 128];
      size_t o = (((size_t)a * CHUNKS + chunk) * SAF + t) * 2;
      part[o] = a1; part[o + 1] = a2;
    }
    __syncthreads();
  }
  {
    int f = t & 31, g = t >> 5;
    const float* p = actions + ((size_t)a * B_N + r0 + g) * OUT_N + f;
    float s1 = 0.f, s2 = 0.f;
    for (int it = 0; it < 32; ++it){
      float v = p[(size_t)(8 * it) * OUT_N];
      s1 += v; s2 += v * v;
    }
    red[t] = s1; red[256 + t] = s2;
    __syncthreads();
    if (t < 32){
      float a1 = 0.f, a2 = 0.f;
      #pragma unroll
      for (int gg = 0; gg < 8; ++gg){
        a1 += red[t + 32 * gg];
        a2 += red[256 + t + 32 * gg];
      }
      size_t o = (((size_t)a * CHUNKS + chunk) * SAF + 128 + t) * 2;
      part[o] = a1; part[o + 1] = a2;
    }
  }
}

__global__ void k_finalize(const float* __restrict__ part,
                           float* __restrict__ meanArr, float* __restrict__ istdArr)
{
  int idx = blockIdx.x * blockDim.x + threadIdx.x;
  if (idx >= A_N * SAF) return;
  int a = idx / SAF, f = idx % SAF;
  float s1 = 0.f, s2 = 0.f;
  for (int c = 0; c < CHUNKS; ++c){
    size_t o = (((size_t)a * CHUNKS + c) * SAF + f) * 2;
    s1 += part[o]; s2 += part[o + 1];
  }
  float m = s1 * (1.f / B_N);
  float v = s2 * (1.f / B_N) - m * m;
  if (v < 0.f) v = 0.f;
  meanArr[idx] = m;
  istdArr[idx] = rsqrtf(v + EPSV);
}

// ---------------------------------------------------------------------------
// Weight pre-pack -> transposed [n][k] bf16 hi/lo pairs (w ~= hi + lo, ~16
// mantissa bits => fp32-quality GEMM when both terms are MFMA'd).
// ---------------------------------------------------------------------------
__device__ __forceinline__ void packpair(float w, u16* __restrict__ dh,
                                         u16* __restrict__ dl, int i){
  u16 h = f2bf(w);
  dh[i] = h;
  dl[i] = f2bf(w - bf2f(h));
}

__global__ __launch_bounds__(256) void k_pack(
    const float* __restrict__ enc_w, const float* __restrict__ aenc_w,
    const float* __restrict__ key_w, const float* __restrict__ sel_w,
    const float* __restrict__ val_w, const float* __restrict__ c1_w,
    u16* __restrict__ encH, u16* __restrict__ encL,
    u16* __restrict__ aencH, u16* __restrict__ aencL,
    u16* __restrict__ keyH, u16* __restrict__ keyL,
    u16* __restrict__ selH, u16* __restrict__ selL,
    u16* __restrict__ valH, u16* __restrict__ valL,
    u16* __restrict__ c1H, u16* __restrict__ c1L)
{
  int i = blockIdx.x * 256 + threadIdx.x;
  const int S0 = A_N * H_N * ENC_KP;   // 196608
  const int S1 = A_N * H_N * OUT_N;    // 32768
  const int S2 = KD_N * H_N;           // 16384
  const int S5 = A_N * H_N * CIN_N;    // 262144
  if (i < S0){
    int a = i / (H_N * ENC_KP); int r = i % (H_N * ENC_KP);
    int n = r / ENC_KP; int k = r % ENC_KP;
    float v = (k < SAF) ? enc_w[((size_t)a * SAF + k) * H_N + n] : 0.f;
    packpair(v, encH, encL, i);
    return;
  }
  i -= S0;
  if (i < S1){
    int a = i / (H_N * OUT_N); int r = i % (H_N * OUT_N);
    int n = r / OUT_N; int k = r % OUT_N;
    packpair(aenc_w[((size_t)a * OUT_N + k) * H_N + n], aencH, aencL, i);
    return;
  }
  i -= S1;
  if (i < 3 * S2){
    int which = i / S2; int j = i % S2;
    int n = j / H_N, k = j % H_N;
    const float* w = (which == 0) ? key_w : ((which == 1) ? sel_w : val_w);
    u16* dh = (which == 0) ? keyH : ((which == 1) ? selH : valH);
    u16* dl = (which == 0) ? keyL : ((which == 1) ? selL : valL);
    packpair(w[(((size_t)(n >> 5)) * H_N + k) * D_N + (n & 31)], dh, dl, j);
    return;
  }
  i -= 3 * S2;
  if (i < S5){
    int a = i / (H_N * CIN_N); int r = i % (H_N * CIN_N);
    int n = r / CIN_N; int k = r % CIN_N;
    packpair(c1_w[((size_t)a * CIN_N + k) * H_N + n], c1H, c1L, i);
  }
}
#define PACK_TOTAL (A_N*H_N*ENC_KP + A_N*H_N*OUT_N + 3*KD_N*H_N + A_N*H_N*CIN_N)

// ---------------------------------------------------------------------------
// Generic MFMA GEMM, 128x128 tile. Every mode accumulates X*Wh + X*Wl.
// SPLIT modes additionally split the fp32 X into xh+xl and add xl*Wh.
// MODE 0: enc   (fp32 BN concat, bias+lrelu, KTOT=192, SPLIT)
// MODE 1: aenc  (fp32 BN actions, bias+lrelu, KTOT=32, SPLIT)
// MODE 2: heads (bf16 in, none)      MODE 3: heads (bf16 in, bias[col]+lrelu)
// MODE 4: critic (two bf16 in, bias+lrelu, fused c2 dot -> qout)
// frag layouts (verified m89/m91): A[m=lane&15][k=quad*8+j]; C col=lane&15,
// row=quad*4+reg. LDS row stride BK+8 (16B-multiple; 2-way conflicts = free).
// ---------------------------------------------------------------------------
template<int KTOT, int MODE, int SPLIT>
__global__ __launch_bounds__(256) void k_mfma_gemm(
    const float* __restrict__ fA, const float* __restrict__ fB,
    const float* __restrict__ mean, const float* __restrict__ istd,
    const u16* __restrict__ xbf1, const u16* __restrict__ xbf2,
    const u16* __restrict__ Wh_g, const u16* __restrict__ Wl_g,
    const float* __restrict__ bias, u16* __restrict__ outbf,
    const float* __restrict__ c2w, const float* __restrict__ c2b,
    float* __restrict__ qout)
{
  constexpr int BK = SPLIT ? 32 : 64;
  constexpr int STR = BK + 8;
  static_assert(KTOT % BK == 0, "K tiling");
  int a = blockIdx.y;
  int row0 = blockIdx.x * 128;
  int t = threadIdx.x;
  int lane = t & 63, wave = t >> 6;
  int l16 = lane & 15, quad = lane >> 4;
  __shared__ __align__(16) u16 Xs[(SPLIT ? 2 : 1) * 128 * STR];
  __shared__ __align__(16) u16 Wh[128 * STR];
  __shared__ __align__(16) u16 Wl[128 * STR];
  u16* Xl = Xs + 128 * STR;   // only touched when SPLIT
  floatx4 acc[2][8];
  #pragma unroll
  for (int mt = 0; mt < 2; ++mt)
    #pragma unroll
    for (int nt = 0; nt < 8; ++nt)
      acc[mt][nt] = (floatx4){0.f, 0.f, 0.f, 0.f};

  const size_t woff = (MODE == 2 || MODE == 3) ? 0 : (size_t)a * H_N * KTOT;
  const u16* wbh = Wh_g + woff;
  const u16* wbl = Wl_g + woff;

  for (int k0 = 0; k0 < KTOT; k0 += BK){
    // ---- stage W hi/lo tiles [128 n][BK k] ----
    for (int c = t; c < 128 * (BK / 8); c += 256){
      int n = c / (BK / 8); int off = (c % (BK / 8)) * 8;
      *(uint4*)&Wh[n * STR + off] = *(const uint4*)(wbh + (size_t)n * KTOT + k0 + off);
      *(uint4*)&Wl[n * STR + off] = *(const uint4*)(wbl + (size_t)n * KTOT + k0 + off);
    }
    // ---- stage X tile [128 rows][BK k] ----
    if (MODE == 0 || MODE == 1){
      for (int e = t; e < 128 * (BK / 2); e += 256){
        int r = e / (BK / 2); int kp = (e % (BK / 2)) * 2;
        int f = k0 + kp;
        size_t row = (size_t)a * B_N + row0 + r;
        float v0 = 0.f, v1 = 0.f;
        if (MODE == 0){
          if (f < IN_N){
            float2 p = *(const float2*)(fA + row * IN_N + f); v0 = p.x; v1 = p.y;
          } else if (f < SAF){
            float2 p = *(const float2*)(fB + row * OUT_N + (f - IN_N)); v0 = p.x; v1 = p.y;
          }
          if (f < SAF){
            v0 = (v0 - mean[a * SAF + f])     * istd[a * SAF + f];
            v1 = (v1 - mean[a * SAF + f + 1]) * istd[a * SAF + f + 1];
          }
        } else {
          float2 p = *(const float2*)(fA + row * OUT_N + f);
          v0 = (p.x - mean[a * SAF + 128 + f])     * istd[a * SAF + 128 + f];
          v1 = (p.y - mean[a * SAF + 128 + f + 1]) * istd[a * SAF + 128 + f + 1];
        }
        u16 h0 = f2bf(v0), h1 = f2bf(v1);
        *(u32*)&Xs[r * STR + kp] = (u32)h0 | ((u32)h1 << 16);
        u16 l0 = f2bf(v0 - bf2f(h0)), l1 = f2bf(v1 - bf2f(h1));
        *(u32*)&Xl[r * STR + kp] = (u32)l0 | ((u32)l1 << 16);
      }
    } else {
      for (int c = t; c < 128 * (BK / 8); c += 256){
        int r = c / (BK / 8); int off = (c % (BK / 8)) * 8;
        int fo = k0 + off;
        const u16* src = xbf1;
        if (MODE == 4 && fo >= H_N){ src = xbf2; fo -= H_N; }
        *(uint4*)&Xs[r * STR + off] =
            *(const uint4*)(src + ((size_t)a * B_N + row0 + r) * H_N + fo);
      }
    }
    __syncthreads();
    #pragma unroll
    for (int ks = 0; ks < BK; ks += 32){
      short8 af[2], al[2], bh[8], bl[8];
      #pragma unroll
      for (int mt = 0; mt < 2; ++mt){
        int rr = (wave * 32 + mt * 16 + l16) * STR + ks + quad * 8;
        af[mt] = *(const short8*)&Xs[rr];
        if (SPLIT) al[mt] = *(const short8*)&Xl[rr];
      }
      #pragma unroll
      for (int nt = 0; nt < 8; ++nt){
        int rr = (nt * 16 + l16) * STR + ks + quad * 8;
        bh[nt] = *(const short8*)&Wh[rr];
        bl[nt] = *(const short8*)&Wl[rr];
      }
      #pragma unroll
      for (int mt = 0; mt < 2; ++mt)
        #pragma unroll
        for (int nt = 0; nt < 8; ++nt){
          acc[mt][nt] = __builtin_amdgcn_mfma_f32_16x16x32_bf16(
              af[mt], bh[nt], acc[mt][nt], 0, 0, 0);
          acc[mt][nt] = __builtin_amdgcn_mfma_f32_16x16x32_bf16(
              af[mt], bl[nt], acc[mt][nt], 0, 0, 0);
          if (SPLIT)
            acc[mt][nt] = __builtin_amdgcn_mfma_f32_16x16x32_bf16(
                al[mt], bh[nt], acc[mt][nt], 0, 0, 0);
        }
    }
    __syncthreads();
  }

  // ---- epilogue ----
  if (MODE == 4){
    float c2r[8], bv[8];
    #pragma unroll
    for (int nt = 0; nt < 8; ++nt){
      c2r[nt] = c2w[a * H_N + nt * 16 + l16];
      bv[nt]  = bias[a * H_N + nt * 16 + l16];
    }
    #pragma unroll
    for (int mt = 0; mt < 2; ++mt){
      #pragma unroll
      for (int r = 0; r < 4; ++r){
        float s = 0.f;
        #pragma unroll
        for (int nt = 0; nt < 8; ++nt){
          float h = lrelu(acc[mt][nt][r] + bv[nt]);
          s = fmaf(h, c2r[nt], s);
        }
        s += __shfl_xor(s, 1);
        s += __shfl_xor(s, 2);
        s += __shfl_xor(s, 4);
        s += __shfl_xor(s, 8);
        if (l16 == 0){
          int row = row0 + wave * 32 + mt * 16 + quad * 4 + r;
          qout[(size_t)a * B_N + row] = s + c2b[a];
        }
      }
    }
  } else {
    #pragma unroll
    for (int nt = 0; nt < 8; ++nt){
      int col = nt * 16 + l16;
      float bv = 0.f;
      if (MODE == 0 || MODE == 1) bv = bias[a * H_N + col];
      if (MODE == 3)              bv = bias[col];
      #pragma unroll
      for (int mt = 0; mt < 2; ++mt){
        #pragma unroll
        for (int r = 0; r < 4; ++r){
          int row = row0 + wave * 32 + mt * 16 + quad * 4 + r;
          float v = acc[mt][nt][r];
          if (MODE == 0 || MODE == 1 || MODE == 3) v = lrelu(v + bv);
          outbf[((size_t)a * B_N + row) * H_N + col] = f2bf(v);
        }
      }
    }
  }
}

// ---------------------------------------------------------------------------
// Attention: block = 8 b-rows, all agents/heads in LDS. `other` may alias
// `keys`: all global reads complete before __syncthreads; rows disjoint
// across blocks.
// ---------------------------------------------------------------------------
__global__ __launch_bounds__(256) void k_attn(
    const u16* __restrict__ sels, const u16* __restrict__ keys,
    const u16* __restrict__ vals, u16* __restrict__ other)
{
  int b0 = blockIdx.x * 8;
  int t = threadIdx.x;
  __shared__ __align__(16) u16 sS[8192], sK[8192], sV[8192];
  u32* dS = (u32*)sS; u32* dK = (u32*)sK; u32* dV = (u32*)sV;
  #pragma unroll
  for (int a = 0; a < 8; ++a){
    size_t go = ((size_t)a * B_N + b0) * KD_N;
    const u32* gs = (const u32*)(sels + go);
    const u32* gk = (const u32*)(keys + go);
    const u32* gv = (const u32*)(vals + go);
    dS[a * 512 + t] = gs[t]; dS[a * 512 + 256 + t] = gs[256 + t];
    dK[a * 512 + t] = gk[t]; dK[a * 512 + 256 + t] = gk[256 + t];
    dV[a * 512 + t] = gv[t]; dV[a * 512 + 256 + t] = gv[256 + t];
  }
  __syncthreads();
  int i = t & 7, p = t >> 3;
  int k = p & 3, bl = p >> 2;
  int base_i = (i * 8 + bl) * 128 + k * 32;
  float si[32];
  {
    const u32* S32 = (const u32*)&sS[base_i];
    #pragma unroll
    for (int d2 = 0; d2 < 16; ++d2){
      u32 u = S32[d2];
      si[2 * d2] = bf_lo(u); si[2 * d2 + 1] = bf_hi(u);
    }
  }
  float lg[8];
  #pragma unroll
  for (int j = 0; j < 8; ++j){
    const u32* K32 = (const u32*)&sK[(j * 8 + bl) * 128 + k * 32];
    float acc = 0.f;
    #pragma unroll
    for (int d2 = 0; d2 < 16; ++d2){
      u32 u = K32[d2];
      acc = fmaf(si[2 * d2], bf_lo(u), acc);
      acc = fmaf(si[2 * d2 + 1], bf_hi(u), acc);
    }
    lg[j] = acc * 0.17677669529663689f;
  }
  float mx = -3.0e38f;
  #pragma unroll
  for (int j = 0; j < 8; ++j) if (j != i) mx = fmaxf(mx, lg[j]);
  float pe[8], se = 0.f;
  #pragma unroll
  for (int j = 0; j < 8; ++j){
    pe[j] = (j == i) ? 0.f : __expf(lg[j] - mx);
    se += pe[j];
  }
  float inv = 1.f / se;
  #pragma unroll
  for (int j = 0; j < 8; ++j) pe[j] *= inv;
  __align__(16) u16 ob[32];
  #pragma unroll
  for (int d2 = 0; d2 < 16; ++d2){
    float acc0 = 0.f, acc1 = 0.f;
    #pragma unroll
    for (int j = 0; j < 8; ++j){
      u32 u = *(const u32*)&sV[(j * 8 + bl) * 128 + k * 32 + 2 * d2];
      acc0 = fmaf(pe[j], bf_lo(u), acc0);
      acc1 = fmaf(pe[j], bf_hi(u), acc1);
    }
    ob[2 * d2] = f2bf(acc0); ob[2 * d2 + 1] = f2bf(acc1);
  }
  uint4* dst = (uint4*)(other + ((size_t)i * B_N + (b0 + bl)) * KD_N + k * 32);
  const uint4* s4 = (const uint4*)ob;
  #pragma unroll
  for (int c = 0; c < 4; ++c) dst[c] = s4[c];
}

// ---------------------------------------------------------------------------
extern "C" void kernel_launch(void* const* d_in, const int* in_sizes, int n_in,
                              void* d_out, int out_size, void* d_ws, size_t ws_size,
                              hipStream_t stream)
{
  const float* states  = (const float*)d_in[0];
  const float* actions = (const float*)d_in[1];
  const float* enc_w   = (const float*)d_in[2];
  const float* enc_b   = (const float*)d_in[3];
  const float* aenc_w  = (const float*)d_in[4];
  const float* aenc_b  = (const float*)d_in[5];
  const float* key_w   = (const float*)d_in[6];
  const float* sel_w   = (const float*)d_in[7];
  const float* val_w   = (const float*)d_in[8];
  const float* val_b   = (const float*)d_in[9];
  const float* c1_w    = (const float*)d_in[10];
  const float* c1_b    = (const float*)d_in[11];
  const float* c2_w    = (const float*)d_in[12];
  const float* c2_b    = (const float*)d_in[13];
  float* q = (float*)d_out;

  char* ws = (char*)d_ws;
  // Pack region [0, 1,114,112) overlaps stats partials [0, 1,310,720):
  // k_stats/k_finalize consume `part` before k_pack overwrites it (same
  // stream, sequential). mean/istd live above both.
  u16* encH  = (u16*)(ws + 0);          // 393216 B
  u16* encL  = (u16*)(ws + 393216);     // 393216 B
  u16* aencH = (u16*)(ws + 786432);     //  65536 B
  u16* aencL = (u16*)(ws + 851968);     //  65536 B
  u16* keyH  = (u16*)(ws + 917504);     //  32768 B
  u16* keyL  = (u16*)(ws + 950272);     //  32768 B
  u16* selH  = (u16*)(ws + 983040);     //  32768 B
  u16* selL  = (u16*)(ws + 1015808);    //  32768 B
  u16* valH  = (u16*)(ws + 1048576);    //  32768 B
  u16* valL  = (u16*)(ws + 1081344);    //  32768 B -> ends 1,114,112
  float* part    = (float*)ws;                 // 1,310,720 B (dead after finalize)
  float* meanArr = (float*)(ws + 1310720);     // 5,120 B
  float* istdArr = (float*)(ws + 1315840);     // 5,120 B
  u16* c1H = (u16*)(ws + 1320960);             // 524,288 B
  u16* c1L = (u16*)(ws + 1845248);             // 524,288 B -> ends 2,369,536
  // Big bf16 activation buffers (4 x 64 MB). Total ws use ~272.6 MB.
  const size_t ibase = 4194304;
  const size_t BUF = (size_t)A_N * B_N * 128 * 2; // 67,108,864 B
  u16* sa_enc = (u16*)(ws + ibase);
  u16* buf2   = (u16*)(ws + ibase + BUF);         // a_enc, later sels
  u16* keys   = (u16*)(ws + ibase + 2 * BUF);     // keys, later `other`
  u16* vals   = (u16*)(ws + ibase + 3 * BUF);

  // c1 pack region overlaps part? c1H starts at 1,320,960 > part end? part
  // ends at 1,310,720 -> no overlap with c1H. mean/istd at [1310720,1320960).

  k_stats<<<dim3(CHUNKS, A_N), 256, 0, stream>>>(states, actions, part);
  k_finalize<<<(A_N * SAF + 255) / 256, 256, 0, stream>>>(part, meanArr, istdArr);
  k_pack<<<(PACK_TOTAL + 255) / 256, 256, 0, stream>>>(
      enc_w, aenc_w, key_w, sel_w, val_w, c1_w,
      encH, encL, aencH, aencL, keyH, keyL, selH, selL, valH, valL, c1H, c1L);

  dim3 g(B_N / 128, A_N);
  k_mfma_gemm<ENC_KP, 0, 1><<<g, 256, 0, stream>>>(
      states, actions, meanArr, istdArr, nullptr, nullptr,
      encH, encL, enc_b, sa_enc, nullptr, nullptr, nullptr);
  k_mfma_gemm<OUT_N, 1, 1><<<g, 256, 0, stream>>>(
      actions, nullptr, meanArr, istdArr, nullptr, nullptr,
      aencH, aencL, aenc_b, buf2, nullptr, nullptr, nullptr);
  k_mfma_gemm<H_N, 2, 0><<<g, 256, 0, stream>>>(
      nullptr, nullptr, nullptr, nullptr, buf2, nullptr,
      keyH, keyL, nullptr, keys, nullptr, nullptr, nullptr);
  k_mfma_gemm<H_N, 3, 0><<<g, 256, 0, stream>>>(
      nullptr, nullptr, nullptr, nullptr, buf2, nullptr,
      valH, valL, val_b, vals, nullptr, nullptr, nullptr);
  k_mfma_gemm<H_N, 2, 0><<<g, 256, 0, stream>>>(
      nullptr, nullptr, nullptr, nullptr, sa_enc, nullptr,
      selH, selL, nullptr, buf2, nullptr, nullptr, nullptr);   // sels -> buf2
  k_attn<<<B_N / 8, 256, 0, stream>>>(buf2, keys, vals, keys); // other -> keys
  k_mfma_gemm<CIN_N, 4, 0><<<g, 256, 0, stream>>>(
      nullptr, nullptr, nullptr, nullptr, sa_enc, keys,
      c1H, c1L, c1_b, nullptr, c2_w, c2_b, q);
}

// Round 4
// 599.526 us; speedup vs baseline: 2.0899x; 1.1188x over previous
//
#include <hip/hip_runtime.h>
#include <hip/hip_bf16.h>
#include <stdint.h>

// Problem constants
#define A_N 8
#define B_N 32768
#define IN_N 128
#define OUT_N 32
#define SAF 160      // IN + OUT
#define H_N 128
#define D_N 32
#define KD_N 128     // K*D
#define CIN_N 256    // critic input = H + K*D
#define CHUNKS 128   // stats chunks over B
#define EPSV 1e-5f
#define ENC_KP 192   // enc K padded 160 -> 192

typedef unsigned int u32;
typedef unsigned short u16;
typedef __attribute__((ext_vector_type(8))) short short8;    // 8 bf16 (4 VGPRs)
typedef __attribute__((ext_vector_type(4))) float floatx4;   // MFMA C/D

__device__ __forceinline__ float bf_lo(u32 u){ return __uint_as_float(u << 16); }
__device__ __forceinline__ float bf_hi(u32 u){ return __uint_as_float(u & 0xffff0000u); }
__device__ __forceinline__ float bf2f(u16 b){ return __uint_as_float(((u32)b) << 16); }
__device__ __forceinline__ u16 f2bf(float f){
  u32 u = __float_as_uint(f);
  return (u16)((u + 0x7fffu + ((u >> 16) & 1u)) >> 16);
}
__device__ __forceinline__ float lrelu(float x){ return x > 0.f ? x : 0.01f * x; }

// ---------------------------------------------------------------------------
// Stage 1: BN statistics (sum, sumsq) per (agent, feature).
// ---------------------------------------------------------------------------
__global__ __launch_bounds__(256) void k_stats(
    const float* __restrict__ states, const float* __restrict__ actions,
    float* __restrict__ part)
{
  int a = blockIdx.y;
  int chunk = blockIdx.x;
  int t = threadIdx.x;
  int r0 = chunk * (B_N / CHUNKS);   // 256 rows per chunk
  __shared__ float red[512];
  {
    int f = t & 127, half = t >> 7;
    const float* p = states + ((size_t)a * B_N + r0 + half) * IN_N + f;
    float s1 = 0.f, s2 = 0.f;
    for (int it = 0; it < 128; ++it){
      float v = p[(size_t)(2 * it) * IN_N];
      s1 += v; s2 += v * v;
    }
    red[t] = s1; red[256 + t] = s2;
    __syncthreads();
    if (t < 128){
      float a1 = red[t] + red[t + 128];
      float a2 = red[256 + t] + red[256 + t + 128];
      size_t o = (((size_t)a * CHUNKS + chunk) * SAF + t) * 2;
      part[o] = a1; part[o + 1] = a2;
    }
    __syncthreads();
  }
  {
    int f = t & 31, g = t >> 5;
    const float* p = actions + ((size_t)a * B_N + r0 + g) * OUT_N + f;
    float s1 = 0.f, s2 = 0.f;
    for (int it = 0; it < 32; ++it){
      float v = p[(size_t)(8 * it) * OUT_N];
      s1 += v; s2 += v * v;
    }
    red[t] = s1; red[256 + t] = s2;
    __syncthreads();
    if (t < 32){
      float a1 = 0.f, a2 = 0.f;
      #pragma unroll
      for (int gg = 0; gg < 8; ++gg){
        a1 += red[t + 32 * gg];
        a2 += red[256 + t + 32 * gg];
      }
      size_t o = (((size_t)a * CHUNKS + chunk) * SAF + 128 + t) * 2;
      part[o] = a1; part[o + 1] = a2;
    }
  }
}

__global__ void k_finalize(const float* __restrict__ part,
                           float* __restrict__ meanArr, float* __restrict__ istdArr)
{
  int idx = blockIdx.x * blockDim.x + threadIdx.x;
  if (idx >= A_N * SAF) return;
  int a = idx / SAF, f = idx % SAF;
  float s1 = 0.f, s2 = 0.f;
  for (int c = 0; c < CHUNKS; ++c){
    size_t o = (((size_t)a * CHUNKS + c) * SAF + f) * 2;
    s1 += part[o]; s2 += part[o + 1];
  }
  float m = s1 * (1.f / B_N);
  float v = s2 * (1.f / B_N) - m * m;
  if (v < 0.f) v = 0.f;
  meanArr[idx] = m;
  istdArr[idx] = rsqrtf(v + EPSV);
}

// ---------------------------------------------------------------------------
// Weight pre-pack -> transposed [n][k] bf16 hi/lo pairs (w ~= hi + lo).
// ---------------------------------------------------------------------------
__device__ __forceinline__ void packpair(float w, u16* __restrict__ dh,
                                         u16* __restrict__ dl, int i){
  u16 h = f2bf(w);
  dh[i] = h;
  dl[i] = f2bf(w - bf2f(h));
}

__global__ __launch_bounds__(256) void k_pack(
    const float* __restrict__ enc_w, const float* __restrict__ aenc_w,
    const float* __restrict__ key_w, const float* __restrict__ sel_w,
    const float* __restrict__ val_w, const float* __restrict__ c1_w,
    u16* __restrict__ encH, u16* __restrict__ encL,
    u16* __restrict__ aencH, u16* __restrict__ aencL,
    u16* __restrict__ keyH, u16* __restrict__ keyL,
    u16* __restrict__ selH, u16* __restrict__ selL,
    u16* __restrict__ valH, u16* __restrict__ valL,
    u16* __restrict__ c1H, u16* __restrict__ c1L)
{
  int i = blockIdx.x * 256 + threadIdx.x;
  const int S0 = A_N * H_N * ENC_KP;   // 196608
  const int S1 = A_N * H_N * OUT_N;    // 32768
  const int S2 = KD_N * H_N;           // 16384
  const int S5 = A_N * H_N * CIN_N;    // 262144
  if (i < S0){
    int a = i / (H_N * ENC_KP); int r = i % (H_N * ENC_KP);
    int n = r / ENC_KP; int k = r % ENC_KP;
    float v = (k < SAF) ? enc_w[((size_t)a * SAF + k) * H_N + n] : 0.f;
    packpair(v, encH, encL, i);
    return;
  }
  i -= S0;
  if (i < S1){
    int a = i / (H_N * OUT_N); int r = i % (H_N * OUT_N);
    int n = r / OUT_N; int k = r % OUT_N;
    packpair(aenc_w[((size_t)a * OUT_N + k) * H_N + n], aencH, aencL, i);
    return;
  }
  i -= S1;
  if (i < 3 * S2){
    int which = i / S2; int j = i % S2;
    int n = j / H_N, k = j % H_N;
    const float* w = (which == 0) ? key_w : ((which == 1) ? sel_w : val_w);
    u16* dh = (which == 0) ? keyH : ((which == 1) ? selH : valH);
    u16* dl = (which == 0) ? keyL : ((which == 1) ? selL : valL);
    packpair(w[(((size_t)(n >> 5)) * H_N + k) * D_N + (n & 31)], dh, dl, j);
    return;
  }
  i -= 3 * S2;
  if (i < S5){
    int a = i / (H_N * CIN_N); int r = i % (H_N * CIN_N);
    int n = r / CIN_N; int k = r % CIN_N;
    packpair(c1_w[((size_t)a * CIN_N + k) * H_N + n], c1H, c1L, i);
  }
}
#define PACK_TOTAL (A_N*H_N*ENC_KP + A_N*H_N*OUT_N + 3*KD_N*H_N + A_N*H_N*CIN_N)

// ---------------------------------------------------------------------------
// Fused kernel 1: sa_enc = lrelu(BN(concat) @ enc_w + enc_b)  [SPLIT, K=192]
//                 sels   = sa_enc @ sel_w                      [2-term, K=128]
// sa_enc tile round-trips through LDS; both outputs stored vectorized.
// frag layouts (verified m89/m91): A[m=lane&15][k=quad*8+j]; C col=lane&15,
// row=quad*4+reg. Staging stride 72 u16 (144B) / tile stride 136 u16 (272B):
// both 16B-multiples, only free 2-way bank conflicts.
// ---------------------------------------------------------------------------
__global__ __launch_bounds__(256, 2) void k_enc_sel(
    const float* __restrict__ states, const float* __restrict__ actions,
    const float* __restrict__ mean, const float* __restrict__ istd,
    const u16* __restrict__ encH, const u16* __restrict__ encL,
    const float* __restrict__ enc_b,
    const u16* __restrict__ selH, const u16* __restrict__ selL,
    u16* __restrict__ sa_enc, u16* __restrict__ sels)
{
  int a = blockIdx.y; int row0 = blockIdx.x * 128; int t = threadIdx.x;
  int lane = t & 63, wave = t >> 6, l16 = lane & 15, quad = lane >> 4;
  __shared__ __align__(16) u16 WA[18432];   // Wh | Wl (BK=64, stride 72)
  __shared__ __align__(16) u16 XA[18432];   // Xh | Xl; later tile T[128][136]
  __shared__ __align__(16) float sc[192], sh[192];
  u16* Wh = WA; u16* Wl = WA + 9216;
  u16* Xh = XA; u16* Xl = XA + 9216;
  u16* T  = XA;

  if (t < 192){
    float m = 0.f, s = 0.f;
    if (t < SAF){ m = mean[a * SAF + t]; s = istd[a * SAF + t]; }
    sc[t] = s; sh[t] = -m * s;
  }
  floatx4 acc[2][8];
  #pragma unroll
  for (int mt = 0; mt < 2; ++mt)
    #pragma unroll
    for (int nt = 0; nt < 8; ++nt) acc[mt][nt] = (floatx4){0.f,0.f,0.f,0.f};
  const u16* wbh = encH + (size_t)a * H_N * ENC_KP;
  const u16* wbl = encL + (size_t)a * H_N * ENC_KP;
  __syncthreads();

  // ---- phase 1: enc GEMM (3-term split) ----
  for (int k0 = 0; k0 < ENC_KP; k0 += 64){
    for (int c = t; c < 1024; c += 256){
      int n = c >> 3, off = (c & 7) * 8;
      *(uint4*)&Wh[n * 72 + off] = *(const uint4*)(wbh + (size_t)n * ENC_KP + k0 + off);
      *(uint4*)&Wl[n * 72 + off] = *(const uint4*)(wbl + (size_t)n * ENC_KP + k0 + off);
    }
    for (int c = t; c < 2048; c += 256){
      int r = c >> 4, kc = (c & 15) * 4, f = k0 + kc;
      size_t row = (size_t)a * B_N + row0 + r;
      float4 v = {0.f, 0.f, 0.f, 0.f};
      if (f < IN_N)     v = *(const float4*)(states + row * IN_N + f);
      else if (f < SAF) v = *(const float4*)(actions + row * OUT_N + (f - IN_N));
      float4 scv = *(const float4*)&sc[f];
      float4 shv = *(const float4*)&sh[f];
      float x0 = fmaf(v.x, scv.x, shv.x), x1 = fmaf(v.y, scv.y, shv.y);
      float x2 = fmaf(v.z, scv.z, shv.z), x3 = fmaf(v.w, scv.w, shv.w);
      u16 h0 = f2bf(x0), h1 = f2bf(x1), h2 = f2bf(x2), h3 = f2bf(x3);
      *(u32*)&Xh[r * 72 + kc]     = (u32)h0 | ((u32)h1 << 16);
      *(u32*)&Xh[r * 72 + kc + 2] = (u32)h2 | ((u32)h3 << 16);
      u16 l0 = f2bf(x0 - bf2f(h0)), l1 = f2bf(x1 - bf2f(h1));
      u16 l2 = f2bf(x2 - bf2f(h2)), l3 = f2bf(x3 - bf2f(h3));
      *(u32*)&Xl[r * 72 + kc]     = (u32)l0 | ((u32)l1 << 16);
      *(u32*)&Xl[r * 72 + kc + 2] = (u32)l2 | ((u32)l3 << 16);
    }
    __syncthreads();
    #pragma unroll
    for (int ks = 0; ks < 64; ks += 32){
      short8 ah[2], al[2], bh[8], bl[8];
      #pragma unroll
      for (int mt = 0; mt < 2; ++mt){
        int rr = (wave * 32 + mt * 16 + l16) * 72 + ks + quad * 8;
        ah[mt] = *(const short8*)&Xh[rr];
        al[mt] = *(const short8*)&Xl[rr];
      }
      #pragma unroll
      for (int nt = 0; nt < 8; ++nt){
        int rr = (nt * 16 + l16) * 72 + ks + quad * 8;
        bh[nt] = *(const short8*)&Wh[rr];
        bl[nt] = *(const short8*)&Wl[rr];
      }
      #pragma unroll
      for (int mt = 0; mt < 2; ++mt)
        #pragma unroll
        for (int nt = 0; nt < 8; ++nt){
          acc[mt][nt] = __builtin_amdgcn_mfma_f32_16x16x32_bf16(ah[mt], bh[nt], acc[mt][nt], 0,0,0);
          acc[mt][nt] = __builtin_amdgcn_mfma_f32_16x16x32_bf16(ah[mt], bl[nt], acc[mt][nt], 0,0,0);
          acc[mt][nt] = __builtin_amdgcn_mfma_f32_16x16x32_bf16(al[mt], bh[nt], acc[mt][nt], 0,0,0);
        }
    }
    __syncthreads();
  }

  // ---- phase-1 epilogue: lrelu+bias -> bf16 tile in LDS ----
  {
    float bv[8];
    #pragma unroll
    for (int nt = 0; nt < 8; ++nt) bv[nt] = enc_b[a * H_N + nt * 16 + l16];
    #pragma unroll
    for (int mt = 0; mt < 2; ++mt)
      #pragma unroll
      for (int nt = 0; nt < 8; ++nt)
        #pragma unroll
        for (int r = 0; r < 4; ++r){
          int rl = wave * 32 + mt * 16 + quad * 4 + r;
          T[rl * 136 + nt * 16 + l16] = f2bf(lrelu(acc[mt][nt][r] + bv[nt]));
        }
  }
  __syncthreads();
  // vectorized sa_enc store from tile
  for (int c = t; c < 2048; c += 256){
    int row = c >> 4, col8 = (c & 15) * 8;
    *(uint4*)(sa_enc + ((size_t)a * B_N + row0 + row) * H_N + col8) =
        *(const uint4*)&T[row * 136 + col8];
  }

  // ---- phase 2: sels = tile @ selT (2-term) ----
  #pragma unroll
  for (int mt = 0; mt < 2; ++mt)
    #pragma unroll
    for (int nt = 0; nt < 8; ++nt) acc[mt][nt] = (floatx4){0.f,0.f,0.f,0.f};
  for (int k0 = 0; k0 < H_N; k0 += 64){
    __syncthreads();
    for (int c = t; c < 1024; c += 256){
      int n = c >> 3, off = (c & 7) * 8;
      *(uint4*)&Wh[n * 72 + off] = *(const uint4*)(selH + (size_t)n * H_N + k0 + off);
      *(uint4*)&Wl[n * 72 + off] = *(const uint4*)(selL + (size_t)n * H_N + k0 + off);
    }
    __syncthreads();
    #pragma unroll
    for (int ks = 0; ks < 64; ks += 32){
      short8 ah[2], bh[8], bl[8];
      #pragma unroll
      for (int mt = 0; mt < 2; ++mt)
        ah[mt] = *(const short8*)&T[(wave * 32 + mt * 16 + l16) * 136 + k0 + ks + quad * 8];
      #pragma unroll
      for (int nt = 0; nt < 8; ++nt){
        int rr = (nt * 16 + l16) * 72 + ks + quad * 8;
        bh[nt] = *(const short8*)&Wh[rr];
        bl[nt] = *(const short8*)&Wl[rr];
      }
      #pragma unroll
      for (int mt = 0; mt < 2; ++mt)
        #pragma unroll
        for (int nt = 0; nt < 8; ++nt){
          acc[mt][nt] = __builtin_amdgcn_mfma_f32_16x16x32_bf16(ah[mt], bh[nt], acc[mt][nt], 0,0,0);
          acc[mt][nt] = __builtin_amdgcn_mfma_f32_16x16x32_bf16(ah[mt], bl[nt], acc[mt][nt], 0,0,0);
        }
    }
  }
  __syncthreads();
  #pragma unroll
  for (int mt = 0; mt < 2; ++mt)
    #pragma unroll
    for (int nt = 0; nt < 8; ++nt)
      #pragma unroll
      for (int r = 0; r < 4; ++r){
        int rl = wave * 32 + mt * 16 + quad * 4 + r;
        T[rl * 136 + nt * 16 + l16] = f2bf(acc[mt][nt][r]);
      }
  __syncthreads();
  for (int c = t; c < 2048; c += 256){
    int row = c >> 4, col8 = (c & 15) * 8;
    *(uint4*)(sels + ((size_t)a * B_N + row0 + row) * H_N + col8) =
        *(const uint4*)&T[row * 136 + col8];
  }
}

// ---------------------------------------------------------------------------
// Fused kernel 2: a_enc = lrelu(BN(actions) @ aenc_w + aenc_b) [SPLIT, K=32]
//                 keys = a_enc @ key_w ; vals = lrelu(a_enc @ val_w + val_b)
// a_enc never touches HBM.
// ---------------------------------------------------------------------------
__global__ __launch_bounds__(256, 2) void k_aenc_kv(
    const float* __restrict__ actions,
    const float* __restrict__ mean, const float* __restrict__ istd,
    const u16* __restrict__ aencH, const u16* __restrict__ aencL,
    const float* __restrict__ aenc_b,
    const u16* __restrict__ keyH, const u16* __restrict__ keyL,
    const u16* __restrict__ valH, const u16* __restrict__ valL,
    const float* __restrict__ val_b,
    u16* __restrict__ keys, u16* __restrict__ vals)
{
  int a = blockIdx.y; int row0 = blockIdx.x * 128; int t = threadIdx.x;
  int lane = t & 63, wave = t >> 6, l16 = lane & 15, quad = lane >> 4;
  __shared__ __align__(16) u16 WA[18432];   // phase1: 2x128x40; phase2: 2x128x72
  __shared__ __align__(16) u16 TA[17408];   // phase1 X staging; then tile [128][136]
  __shared__ __align__(16) float sc[32], sh[32];
  u16* T = TA;

  if (t < 32){
    float m = mean[a * SAF + 128 + t], s = istd[a * SAF + 128 + t];
    sc[t] = s; sh[t] = -m * s;
  }
  floatx4 acc[2][8];
  #pragma unroll
  for (int mt = 0; mt < 2; ++mt)
    #pragma unroll
    for (int nt = 0; nt < 8; ++nt) acc[mt][nt] = (floatx4){0.f,0.f,0.f,0.f};
  __syncthreads();

  // ---- phase 1: aenc GEMM, K=32 single tile (stride 40) ----
  {
    u16* Xh = TA; u16* Xl = TA + 5120;
    u16* Wh1 = WA; u16* Wl1 = WA + 5120;
    const u16* wbh = aencH + (size_t)a * H_N * OUT_N;
    const u16* wbl = aencL + (size_t)a * H_N * OUT_N;
    for (int c = t; c < 512; c += 256){
      int n = c >> 2, off = (c & 3) * 8;
      *(uint4*)&Wh1[n * 40 + off] = *(const uint4*)(wbh + (size_t)n * OUT_N + off);
      *(uint4*)&Wl1[n * 40 + off] = *(const uint4*)(wbl + (size_t)n * OUT_N + off);
    }
    for (int c = t; c < 1024; c += 256){
      int r = c >> 3, kc = (c & 7) * 4;
      size_t row = (size_t)a * B_N + row0 + r;
      float4 v = *(const float4*)(actions + row * OUT_N + kc);
      float4 scv = *(const float4*)&sc[kc];
      float4 shv = *(const float4*)&sh[kc];
      float x0 = fmaf(v.x, scv.x, shv.x), x1 = fmaf(v.y, scv.y, shv.y);
      float x2 = fmaf(v.z, scv.z, shv.z), x3 = fmaf(v.w, scv.w, shv.w);
      u16 h0 = f2bf(x0), h1 = f2bf(x1), h2 = f2bf(x2), h3 = f2bf(x3);
      *(u32*)&Xh[r * 40 + kc]     = (u32)h0 | ((u32)h1 << 16);
      *(u32*)&Xh[r * 40 + kc + 2] = (u32)h2 | ((u32)h3 << 16);
      u16 l0 = f2bf(x0 - bf2f(h0)), l1 = f2bf(x1 - bf2f(h1));
      u16 l2 = f2bf(x2 - bf2f(h2)), l3 = f2bf(x3 - bf2f(h3));
      *(u32*)&Xl[r * 40 + kc]     = (u32)l0 | ((u32)l1 << 16);
      *(u32*)&Xl[r * 40 + kc + 2] = (u32)l2 | ((u32)l3 << 16);
    }
    __syncthreads();
    short8 ah[2], al[2], bh[8], bl[8];
    #pragma unroll
    for (int mt = 0; mt < 2; ++mt){
      int rr = (wave * 32 + mt * 16 + l16) * 40 + quad * 8;
      ah[mt] = *(const short8*)&Xh[rr];
      al[mt] = *(const short8*)&Xl[rr];
    }
    #pragma unroll
    for (int nt = 0; nt < 8; ++nt){
      int rr = (nt * 16 + l16) * 40 + quad * 8;
      bh[nt] = *(const short8*)&Wh1[rr];
      bl[nt] = *(const short8*)&Wl1[rr];
    }
    #pragma unroll
    for (int mt = 0; mt < 2; ++mt)
      #pragma unroll
      for (int nt = 0; nt < 8; ++nt){
        acc[mt][nt] = __builtin_amdgcn_mfma_f32_16x16x32_bf16(ah[mt], bh[nt], acc[mt][nt], 0,0,0);
        acc[mt][nt] = __builtin_amdgcn_mfma_f32_16x16x32_bf16(ah[mt], bl[nt], acc[mt][nt], 0,0,0);
        acc[mt][nt] = __builtin_amdgcn_mfma_f32_16x16x32_bf16(al[mt], bh[nt], acc[mt][nt], 0,0,0);
      }
    __syncthreads();
  }
  // a_enc -> LDS tile
  {
    float bv[8];
    #pragma unroll
    for (int nt = 0; nt < 8; ++nt) bv[nt] = aenc_b[a * H_N + nt * 16 + l16];
    #pragma unroll
    for (int mt = 0; mt < 2; ++mt)
      #pragma unroll
      for (int nt = 0; nt < 8; ++nt)
        #pragma unroll
        for (int r = 0; r < 4; ++r){
          int rl = wave * 32 + mt * 16 + quad * 4 + r;
          T[rl * 136 + nt * 16 + l16] = f2bf(lrelu(acc[mt][nt][r] + bv[nt]));
        }
  }

  // ---- phase 2a: keys = tile @ keyT ----
  u16* Wh = WA; u16* Wl = WA + 9216;
  #pragma unroll
  for (int mt = 0; mt < 2; ++mt)
    #pragma unroll
    for (int nt = 0; nt < 8; ++nt) acc[mt][nt] = (floatx4){0.f,0.f,0.f,0.f};
  for (int k0 = 0; k0 < H_N; k0 += 64){
    __syncthreads();
    for (int c = t; c < 1024; c += 256){
      int n = c >> 3, off = (c & 7) * 8;
      *(uint4*)&Wh[n * 72 + off] = *(const uint4*)(keyH + (size_t)n * H_N + k0 + off);
      *(uint4*)&Wl[n * 72 + off] = *(const uint4*)(keyL + (size_t)n * H_N + k0 + off);
    }
    __syncthreads();
    #pragma unroll
    for (int ks = 0; ks < 64; ks += 32){
      short8 ah[2], bh[8], bl[8];
      #pragma unroll
      for (int mt = 0; mt < 2; ++mt)
        ah[mt] = *(const short8*)&T[(wave * 32 + mt * 16 + l16) * 136 + k0 + ks + quad * 8];
      #pragma unroll
      for (int nt = 0; nt < 8; ++nt){
        int rr = (nt * 16 + l16) * 72 + ks + quad * 8;
        bh[nt] = *(const short8*)&Wh[rr];
        bl[nt] = *(const short8*)&Wl[rr];
      }
      #pragma unroll
      for (int mt = 0; mt < 2; ++mt)
        #pragma unroll
        for (int nt = 0; nt < 8; ++nt){
          acc[mt][nt] = __builtin_amdgcn_mfma_f32_16x16x32_bf16(ah[mt], bh[nt], acc[mt][nt], 0,0,0);
          acc[mt][nt] = __builtin_amdgcn_mfma_f32_16x16x32_bf16(ah[mt], bl[nt], acc[mt][nt], 0,0,0);
        }
    }
  }
  // keys epilogue: scalar stores (tile still needed for vals)
  #pragma unroll
  for (int mt = 0; mt < 2; ++mt)
    #pragma unroll
    for (int nt = 0; nt < 8; ++nt)
      #pragma unroll
      for (int r = 0; r < 4; ++r){
        int rl = wave * 32 + mt * 16 + quad * 4 + r;
        keys[((size_t)a * B_N + row0 + rl) * H_N + nt * 16 + l16] = f2bf(acc[mt][nt][r]);
      }

  // ---- phase 2b: vals = lrelu(tile @ valT + val_b) ----
  #pragma unroll
  for (int mt = 0; mt < 2; ++mt)
    #pragma unroll
    for (int nt = 0; nt < 8; ++nt) acc[mt][nt] = (floatx4){0.f,0.f,0.f,0.f};
  for (int k0 = 0; k0 < H_N; k0 += 64){
    __syncthreads();
    for (int c = t; c < 1024; c += 256){
      int n = c >> 3, off = (c & 7) * 8;
      *(uint4*)&Wh[n * 72 + off] = *(const uint4*)(valH + (size_t)n * H_N + k0 + off);
      *(uint4*)&Wl[n * 72 + off] = *(const uint4*)(valL + (size_t)n * H_N + k0 + off);
    }
    __syncthreads();
    #pragma unroll
    for (int ks = 0; ks < 64; ks += 32){
      short8 ah[2], bh[8], bl[8];
      #pragma unroll
      for (int mt = 0; mt < 2; ++mt)
        ah[mt] = *(const short8*)&T[(wave * 32 + mt * 16 + l16) * 136 + k0 + ks + quad * 8];
      #pragma unroll
      for (int nt = 0; nt < 8; ++nt){
        int rr = (nt * 16 + l16) * 72 + ks + quad * 8;
        bh[nt] = *(const short8*)&Wh[rr];
        bl[nt] = *(const short8*)&Wl[rr];
      }
      #pragma unroll
      for (int mt = 0; mt < 2; ++mt)
        #pragma unroll
        for (int nt = 0; nt < 8; ++nt){
          acc[mt][nt] = __builtin_amdgcn_mfma_f32_16x16x32_bf16(ah[mt], bh[nt], acc[mt][nt], 0,0,0);
          acc[mt][nt] = __builtin_amdgcn_mfma_f32_16x16x32_bf16(ah[mt], bl[nt], acc[mt][nt], 0,0,0);
        }
    }
  }
  __syncthreads();
  // vals epilogue: through tile, vectorized
  {
    float bv[8];
    #pragma unroll
    for (int nt = 0; nt < 8; ++nt) bv[nt] = val_b[nt * 16 + l16];
    #pragma unroll
    for (int mt = 0; mt < 2; ++mt)
      #pragma unroll
      for (int nt = 0; nt < 8; ++nt)
        #pragma unroll
        for (int r = 0; r < 4; ++r){
          int rl = wave * 32 + mt * 16 + quad * 4 + r;
          T[rl * 136 + nt * 16 + l16] = f2bf(lrelu(acc[mt][nt][r] + bv[nt]));
        }
  }
  __syncthreads();
  for (int c = t; c < 2048; c += 256){
    int row = c >> 4, col8 = (c & 15) * 8;
    *(uint4*)(vals + ((size_t)a * B_N + row0 + row) * H_N + col8) =
        *(const uint4*)&T[row * 136 + col8];
  }
}

// ---------------------------------------------------------------------------
// Attention: block = 8 b-rows, all agents/heads in LDS. `other` may alias
// `keys` (all global reads complete before __syncthreads; rows disjoint
// across blocks).
// ---------------------------------------------------------------------------
__global__ __launch_bounds__(256) void k_attn(
    const u16* __restrict__ sels, const u16* __restrict__ keys,
    const u16* __restrict__ vals, u16* __restrict__ other)
{
  int b0 = blockIdx.x * 8;
  int t = threadIdx.x;
  __shared__ __align__(16) u16 sS[8192], sK[8192], sV[8192];
  u32* dS = (u32*)sS; u32* dK = (u32*)sK; u32* dV = (u32*)sV;
  #pragma unroll
  for (int a = 0; a < 8; ++a){
    size_t go = ((size_t)a * B_N + b0) * KD_N;
    const u32* gs = (const u32*)(sels + go);
    const u32* gk = (const u32*)(keys + go);
    const u32* gv = (const u32*)(vals + go);
    dS[a * 512 + t] = gs[t]; dS[a * 512 + 256 + t] = gs[256 + t];
    dK[a * 512 + t] = gk[t]; dK[a * 512 + 256 + t] = gk[256 + t];
    dV[a * 512 + t] = gv[t]; dV[a * 512 + 256 + t] = gv[256 + t];
  }
  __syncthreads();
  int i = t & 7, p = t >> 3;
  int k = p & 3, bl = p >> 2;
  int base_i = (i * 8 + bl) * 128 + k * 32;
  float si[32];
  {
    const u32* S32 = (const u32*)&sS[base_i];
    #pragma unroll
    for (int d2 = 0; d2 < 16; ++d2){
      u32 u = S32[d2];
      si[2 * d2] = bf_lo(u); si[2 * d2 + 1] = bf_hi(u);
    }
  }
  float lg[8];
  #pragma unroll
  for (int j = 0; j < 8; ++j){
    const u32* K32 = (const u32*)&sK[(j * 8 + bl) * 128 + k * 32];
    float acc = 0.f;
    #pragma unroll
    for (int d2 = 0; d2 < 16; ++d2){
      u32 u = K32[d2];
      acc = fmaf(si[2 * d2], bf_lo(u), acc);
      acc = fmaf(si[2 * d2 + 1], bf_hi(u), acc);
    }
    lg[j] = acc * 0.17677669529663689f;
  }
  float mx = -3.0e38f;
  #pragma unroll
  for (int j = 0; j < 8; ++j) if (j != i) mx = fmaxf(mx, lg[j]);
  float pe[8], se = 0.f;
  #pragma unroll
  for (int j = 0; j < 8; ++j){
    pe[j] = (j == i) ? 0.f : __expf(lg[j] - mx);
    se += pe[j];
  }
  float inv = 1.f / se;
  #pragma unroll
  for (int j = 0; j < 8; ++j) pe[j] *= inv;
  __align__(16) u16 ob[32];
  #pragma unroll
  for (int d2 = 0; d2 < 16; ++d2){
    float acc0 = 0.f, acc1 = 0.f;
    #pragma unroll
    for (int j = 0; j < 8; ++j){
      u32 u = *(const u32*)&sV[(j * 8 + bl) * 128 + k * 32 + 2 * d2];
      acc0 = fmaf(pe[j], bf_lo(u), acc0);
      acc1 = fmaf(pe[j], bf_hi(u), acc1);
    }
    ob[2 * d2] = f2bf(acc0); ob[2 * d2 + 1] = f2bf(acc1);
  }
  uint4* dst = (uint4*)(other + ((size_t)i * B_N + (b0 + bl)) * KD_N + k * 32);
  const uint4* s4 = (const uint4*)ob;
  #pragma unroll
  for (int c = 0; c < 4; ++c) dst[c] = s4[c];
}

// ---------------------------------------------------------------------------
// Critic: h = lrelu([sa_enc|other] @ c1_w + c1_b); q = h . c2_w + c2_b
// 2-term hi/lo, K=256, BK=64.
// ---------------------------------------------------------------------------
__global__ __launch_bounds__(256, 2) void k_critic(
    const u16* __restrict__ sa_enc, const u16* __restrict__ other,
    const u16* __restrict__ c1H, const u16* __restrict__ c1L,
    const float* __restrict__ c1_b,
    const float* __restrict__ c2w, const float* __restrict__ c2b,
    float* __restrict__ qout)
{
  int a = blockIdx.y; int row0 = blockIdx.x * 128; int t = threadIdx.x;
  int lane = t & 63, wave = t >> 6, l16 = lane & 15, quad = lane >> 4;
  __shared__ __align__(16) u16 Xs[9216];
  __shared__ __align__(16) u16 Wh[9216];
  __shared__ __align__(16) u16 Wl[9216];
  floatx4 acc[2][8];
  #pragma unroll
  for (int mt = 0; mt < 2; ++mt)
    #pragma unroll
    for (int nt = 0; nt < 8; ++nt) acc[mt][nt] = (floatx4){0.f,0.f,0.f,0.f};
  const u16* wbh = c1H + (size_t)a * H_N * CIN_N;
  const u16* wbl = c1L + (size_t)a * H_N * CIN_N;

  for (int k0 = 0; k0 < CIN_N; k0 += 64){
    for (int c = t; c < 1024; c += 256){
      int n = c >> 3, off = (c & 7) * 8;
      *(uint4*)&Wh[n * 72 + off] = *(const uint4*)(wbh + (size_t)n * CIN_N + k0 + off);
      *(uint4*)&Wl[n * 72 + off] = *(const uint4*)(wbl + (size_t)n * CIN_N + k0 + off);
    }
    for (int c = t; c < 1024; c += 256){
      int r = c >> 3, off = (c & 7) * 8;
      int fo = k0 + off;
      const u16* src = sa_enc;
      if (fo >= H_N){ src = other; fo -= H_N; }
      *(uint4*)&Xs[r * 72 + off] =
          *(const uint4*)(src + ((size_t)a * B_N + row0 + r) * H_N + fo);
    }
    __syncthreads();
    #pragma unroll
    for (int ks = 0; ks < 64; ks += 32){
      short8 ah[2], bh[8], bl[8];
      #pragma unroll
      for (int mt = 0; mt < 2; ++mt)
        ah[mt] = *(const short8*)&Xs[(wave * 32 + mt * 16 + l16) * 72 + ks + quad * 8];
      #pragma unroll
      for (int nt = 0; nt < 8; ++nt){
        int rr = (nt * 16 + l16) * 72 + ks + quad * 8;
        bh[nt] = *(const short8*)&Wh[rr];
        bl[nt] = *(const short8*)&Wl[rr];
      }
      #pragma unroll
      for (int mt = 0; mt < 2; ++mt)
        #pragma unroll
        for (int nt = 0; nt < 8; ++nt){
          acc[mt][nt] = __builtin_amdgcn_mfma_f32_16x16x32_bf16(ah[mt], bh[nt], acc[mt][nt], 0,0,0);
          acc[mt][nt] = __builtin_amdgcn_mfma_f32_16x16x32_bf16(ah[mt], bl[nt], acc[mt][nt], 0,0,0);
        }
    }
    __syncthreads();
  }

  float c2r[8], bv[8];
  #pragma unroll
  for (int nt = 0; nt < 8; ++nt){
    c2r[nt] = c2w[a * H_N + nt * 16 + l16];
    bv[nt]  = c1_b[a * H_N + nt * 16 + l16];
  }
  #pragma unroll
  for (int mt = 0; mt < 2; ++mt){
    #pragma unroll
    for (int r = 0; r < 4; ++r){
      float s = 0.f;
      #pragma unroll
      for (int nt = 0; nt < 8; ++nt){
        float h = lrelu(acc[mt][nt][r] + bv[nt]);
        s = fmaf(h, c2r[nt], s);
      }
      s += __shfl_xor(s, 1);
      s += __shfl_xor(s, 2);
      s += __shfl_xor(s, 4);
      s += __shfl_xor(s, 8);
      if (l16 == 0){
        int row = row0 + wave * 32 + mt * 16 + quad * 4 + r;
        qout[(size_t)a * B_N + row] = s + c2b[a];
      }
    }
  }
}

// ---------------------------------------------------------------------------
extern "C" void kernel_launch(void* const* d_in, const int* in_sizes, int n_in,
                              void* d_out, int out_size, void* d_ws, size_t ws_size,
                              hipStream_t stream)
{
  const float* states  = (const float*)d_in[0];
  const float* actions = (const float*)d_in[1];
  const float* enc_w   = (const float*)d_in[2];
  const float* enc_b   = (const float*)d_in[3];
  const float* aenc_w  = (const float*)d_in[4];
  const float* aenc_b  = (const float*)d_in[5];
  const float* key_w   = (const float*)d_in[6];
  const float* sel_w   = (const float*)d_in[7];
  const float* val_w   = (const float*)d_in[8];
  const float* val_b   = (const float*)d_in[9];
  const float* c1_w    = (const float*)d_in[10];
  const float* c1_b    = (const float*)d_in[11];
  const float* c2_w    = (const float*)d_in[12];
  const float* c2_b    = (const float*)d_in[13];
  float* q = (float*)d_out;

  char* ws = (char*)d_ws;
  // Pack region [0, 1,114,112) overlaps stats partials [0, 1,310,720):
  // stats/finalize consume `part` before k_pack overwrites (sequential stream).
  u16* encH  = (u16*)(ws + 0);
  u16* encL  = (u16*)(ws + 393216);
  u16* aencH = (u16*)(ws + 786432);
  u16* aencL = (u16*)(ws + 851968);
  u16* keyH  = (u16*)(ws + 917504);
  u16* keyL  = (u16*)(ws + 950272);
  u16* selH  = (u16*)(ws + 983040);
  u16* selL  = (u16*)(ws + 1015808);
  u16* valH  = (u16*)(ws + 1048576);
  u16* valL  = (u16*)(ws + 1081344);
  float* part    = (float*)ws;
  float* meanArr = (float*)(ws + 1310720);
  float* istdArr = (float*)(ws + 1315840);
  u16* c1H = (u16*)(ws + 1320960);
  u16* c1L = (u16*)(ws + 1845248);
  const size_t ibase = 4194304;
  const size_t BUF = (size_t)A_N * B_N * 128 * 2;   // 64 MB
  u16* sa_enc = (u16*)(ws + ibase);
  u16* sels   = (u16*)(ws + ibase + BUF);
  u16* keys   = (u16*)(ws + ibase + 2 * BUF);       // keys, later `other`
  u16* vals   = (u16*)(ws + ibase + 3 * BUF);

  k_stats<<<dim3(CHUNKS, A_N), 256, 0, stream>>>(states, actions, part);
  k_finalize<<<(A_N * SAF + 255) / 256, 256, 0, stream>>>(part, meanArr, istdArr);
  k_pack<<<(PACK_TOTAL + 255) / 256, 256, 0, stream>>>(
      enc_w, aenc_w, key_w, sel_w, val_w, c1_w,
      encH, encL, aencH, aencL, keyH, keyL, selH, selL, valH, valL, c1H, c1L);

  dim3 g(B_N / 128, A_N);
  k_enc_sel<<<g, 256, 0, stream>>>(states, actions, meanArr, istdArr,
                                   encH, encL, enc_b, selH, selL, sa_enc, sels);
  k_aenc_kv<<<g, 256, 0, stream>>>(actions, meanArr, istdArr,
                                   aencH, aencL, aenc_b, keyH, keyL,
                                   valH, valL, val_b, keys, vals);
  k_attn<<<B_N / 8, 256, 0, stream>>>(sels, keys, vals, keys);  // other -> keys
  k_critic<<<g, 256, 0, stream>>>(sa_enc, keys, c1H, c1L, c1_b, c2_w, c2_b, q);
}

// Round 5
// 543.271 us; speedup vs baseline: 2.3063x; 1.1035x over previous
//
#include <hip/hip_runtime.h>
#include <hip/hip_bf16.h>
#include <stdint.h>

// Problem constants
#define A_N 8
#define B_N 32768
#define IN_N 128
#define OUT_N 32
#define SAF 160      // IN + OUT
#define H_N 128
#define D_N 32
#define KD_N 128     // K*D
#define CIN_N 256    // critic input = H + K*D
#define CHUNKS 128   // stats chunks over B
#define EPSV 1e-5f
#define ENC_KP 192   // enc K padded 160 -> 192

typedef unsigned int u32;
typedef unsigned short u16;
typedef __attribute__((ext_vector_type(8))) short short8;    // 8 bf16 (4 VGPRs)
typedef __attribute__((ext_vector_type(4))) float floatx4;   // MFMA C/D

__device__ __forceinline__ float bf_lo(u32 u){ return __uint_as_float(u << 16); }
__device__ __forceinline__ float bf_hi(u32 u){ return __uint_as_float(u & 0xffff0000u); }
__device__ __forceinline__ float bf2f(u16 b){ return __uint_as_float(((u32)b) << 16); }
__device__ __forceinline__ u16 f2bf(float f){
  u32 u = __float_as_uint(f);
  return (u16)((u + 0x7fffu + ((u >> 16) & 1u)) >> 16);
}
__device__ __forceinline__ float lrelu(float x){ return x > 0.f ? x : 0.01f * x; }

// ---------------------------------------------------------------------------
// Stage 1: BN statistics (sum, sumsq) per (agent, feature).
// ---------------------------------------------------------------------------
__global__ __launch_bounds__(256) void k_stats(
    const float* __restrict__ states, const float* __restrict__ actions,
    float* __restrict__ part)
{
  int a = blockIdx.y;
  int chunk = blockIdx.x;
  int t = threadIdx.x;
  int r0 = chunk * (B_N / CHUNKS);   // 256 rows per chunk
  __shared__ float red[512];
  {
    int f = t & 127, half = t >> 7;
    const float* p = states + ((size_t)a * B_N + r0 + half) * IN_N + f;
    float s1 = 0.f, s2 = 0.f;
    for (int it = 0; it < 128; ++it){
      float v = p[(size_t)(2 * it) * IN_N];
      s1 += v; s2 += v * v;
    }
    red[t] = s1; red[256 + t] = s2;
    __syncthreads();
    if (t < 128){
      float a1 = red[t] + red[t + 128];
      float a2 = red[256 + t] + red[256 + t + 128];
      size_t o = (((size_t)a * CHUNKS + chunk) * SAF + t) * 2;
      part[o] = a1; part[o + 1] = a2;
    }
    __syncthreads();
  }
  {
    int f = t & 31, g = t >> 5;
    const float* p = actions + ((size_t)a * B_N + r0 + g) * OUT_N + f;
    float s1 = 0.f, s2 = 0.f;
    for (int it = 0; it < 32; ++it){
      float v = p[(size_t)(8 * it) * OUT_N];
      s1 += v; s2 += v * v;
    }
    red[t] = s1; red[256 + t] = s2;
    __syncthreads();
    if (t < 32){
      float a1 = 0.f, a2 = 0.f;
      #pragma unroll
      for (int gg = 0; gg < 8; ++gg){
        a1 += red[t + 32 * gg];
        a2 += red[256 + t + 32 * gg];
      }
      size_t o = (((size_t)a * CHUNKS + chunk) * SAF + 128 + t) * 2;
      part[o] = a1; part[o + 1] = a2;
    }
  }
}

__global__ void k_finalize(const float* __restrict__ part,
                           float* __restrict__ meanArr, float* __restrict__ istdArr)
{
  int idx = blockIdx.x * blockDim.x + threadIdx.x;
  if (idx >= A_N * SAF) return;
  int a = idx / SAF, f = idx % SAF;
  float s1 = 0.f, s2 = 0.f;
  for (int c = 0; c < CHUNKS; ++c){
    size_t o = (((size_t)a * CHUNKS + c) * SAF + f) * 2;
    s1 += part[o]; s2 += part[o + 1];
  }
  float m = s1 * (1.f / B_N);
  float v = s2 * (1.f / B_N) - m * m;
  if (v < 0.f) v = 0.f;
  meanArr[idx] = m;
  istdArr[idx] = rsqrtf(v + EPSV);
}

// ---------------------------------------------------------------------------
// Weight pre-pack: enc/aenc/c1 -> transposed bf16 hi/lo pairs (fp32-quality);
// key/sel/val -> transposed single bf16 (error budget allows).
// ---------------------------------------------------------------------------
__device__ __forceinline__ void packpair(float w, u16* __restrict__ dh,
                                         u16* __restrict__ dl, int i){
  u16 h = f2bf(w);
  dh[i] = h;
  dl[i] = f2bf(w - bf2f(h));
}

__global__ __launch_bounds__(256) void k_pack(
    const float* __restrict__ enc_w, const float* __restrict__ aenc_w,
    const float* __restrict__ key_w, const float* __restrict__ sel_w,
    const float* __restrict__ val_w, const float* __restrict__ c1_w,
    u16* __restrict__ encH, u16* __restrict__ encL,
    u16* __restrict__ aencH, u16* __restrict__ aencL,
    u16* __restrict__ keyH, u16* __restrict__ selH, u16* __restrict__ valH,
    u16* __restrict__ c1H, u16* __restrict__ c1L)
{
  int i = blockIdx.x * 256 + threadIdx.x;
  const int S0 = A_N * H_N * ENC_KP;   // 196608
  const int S1 = A_N * H_N * OUT_N;    // 32768
  const int S2 = KD_N * H_N;           // 16384
  const int S5 = A_N * H_N * CIN_N;    // 262144
  if (i < S0){
    int a = i / (H_N * ENC_KP); int r = i % (H_N * ENC_KP);
    int n = r / ENC_KP; int k = r % ENC_KP;
    float v = (k < SAF) ? enc_w[((size_t)a * SAF + k) * H_N + n] : 0.f;
    packpair(v, encH, encL, i);
    return;
  }
  i -= S0;
  if (i < S1){
    int a = i / (H_N * OUT_N); int r = i % (H_N * OUT_N);
    int n = r / OUT_N; int k = r % OUT_N;
    packpair(aenc_w[((size_t)a * OUT_N + k) * H_N + n], aencH, aencL, i);
    return;
  }
  i -= S1;
  if (i < 3 * S2){
    int which = i / S2; int j = i % S2;
    int n = j / H_N, k = j % H_N;
    const float* w = (which == 0) ? key_w : ((which == 1) ? sel_w : val_w);
    u16* dh = (which == 0) ? keyH : ((which == 1) ? selH : valH);
    dh[j] = f2bf(w[(((size_t)(n >> 5)) * H_N + k) * D_N + (n & 31)]);
    return;
  }
  i -= 3 * S2;
  if (i < S5){
    int a = i / (H_N * CIN_N); int r = i % (H_N * CIN_N);
    int n = r / CIN_N; int k = r % CIN_N;
    packpair(c1_w[((size_t)a * CIN_N + k) * H_N + n], c1H, c1L, i);
  }
}
#define PACK_TOTAL (A_N*H_N*ENC_KP + A_N*H_N*OUT_N + 3*KD_N*H_N + A_N*H_N*CIN_N)

// ---------------------------------------------------------------------------
// Fused kernel 1: sa_enc = lrelu(BN(concat) @ enc_w + enc_b)  [3-term, BK=32]
//                 sels   = sa_enc @ sel_w                      [1-term, BK=32]
// LDS arena 45056 B (+ BN tables) -> 3 blocks/CU.
// frag layouts (verified m89/m91): A[m=lane&15][k=quad*8+j]; C col=lane&15,
// row=quad*4+reg. Strides 40/136 u16: 16B-multiple, 2-way conflicts only.
// ---------------------------------------------------------------------------
__global__ __launch_bounds__(256, 3) void k_enc_sel(
    const float* __restrict__ states, const float* __restrict__ actions,
    const float* __restrict__ mean, const float* __restrict__ istd,
    const u16* __restrict__ encH, const u16* __restrict__ encL,
    const float* __restrict__ enc_b,
    const u16* __restrict__ selH,
    u16* __restrict__ sa_enc, u16* __restrict__ sels)
{
  int a = blockIdx.y; int row0 = blockIdx.x * 128; int t = threadIdx.x;
  int lane = t & 63, wave = t >> 6, l16 = lane & 15, quad = lane >> 4;
  __shared__ __align__(16) u16 S[22528];
  __shared__ __align__(16) float sc[192], sh[192];
  u16* Wh = S;            // [128][40]
  u16* Wl = S + 5120;
  u16* Xh = S + 10240;
  u16* Xl = S + 15360;
  u16* T  = S;            // [128][136] (phase 2)
  u16* Ws = S + 17408;    // [128][40]  (phase 2 sel weights)

  if (t < 192){
    float m = 0.f, s = 0.f;
    if (t < SAF){ m = mean[a * SAF + t]; s = istd[a * SAF + t]; }
    sc[t] = s; sh[t] = -m * s;
  }
  floatx4 acc[2][8];
  #pragma unroll
  for (int mt = 0; mt < 2; ++mt)
    #pragma unroll
    for (int nt = 0; nt < 8; ++nt) acc[mt][nt] = (floatx4){0.f,0.f,0.f,0.f};
  const u16* wbh = encH + (size_t)a * H_N * ENC_KP;
  const u16* wbl = encL + (size_t)a * H_N * ENC_KP;
  __syncthreads();

  // ---- phase 1: enc GEMM (3-term split), BK=32 ----
  for (int k0 = 0; k0 < ENC_KP; k0 += 32){
    for (int c = t; c < 512; c += 256){
      int n = c >> 2, off = (c & 3) * 8;
      *(uint4*)&Wh[n * 40 + off] = *(const uint4*)(wbh + (size_t)n * ENC_KP + k0 + off);
      *(uint4*)&Wl[n * 40 + off] = *(const uint4*)(wbl + (size_t)n * ENC_KP + k0 + off);
    }
    for (int c = t; c < 1024; c += 256){
      int r = c >> 3, kc = (c & 7) * 4, f = k0 + kc;
      size_t row = (size_t)a * B_N + row0 + r;
      float4 v = {0.f, 0.f, 0.f, 0.f};
      if (f < IN_N)     v = *(const float4*)(states + row * IN_N + f);
      else if (f < SAF) v = *(const float4*)(actions + row * OUT_N + (f - IN_N));
      float4 scv = *(const float4*)&sc[f];
      float4 shv = *(const float4*)&sh[f];
      float x0 = fmaf(v.x, scv.x, shv.x), x1 = fmaf(v.y, scv.y, shv.y);
      float x2 = fmaf(v.z, scv.z, shv.z), x3 = fmaf(v.w, scv.w, shv.w);
      u16 h0 = f2bf(x0), h1 = f2bf(x1), h2 = f2bf(x2), h3 = f2bf(x3);
      *(u32*)&Xh[r * 40 + kc]     = (u32)h0 | ((u32)h1 << 16);
      *(u32*)&Xh[r * 40 + kc + 2] = (u32)h2 | ((u32)h3 << 16);
      u16 l0 = f2bf(x0 - bf2f(h0)), l1 = f2bf(x1 - bf2f(h1));
      u16 l2 = f2bf(x2 - bf2f(h2)), l3 = f2bf(x3 - bf2f(h3));
      *(u32*)&Xl[r * 40 + kc]     = (u32)l0 | ((u32)l1 << 16);
      *(u32*)&Xl[r * 40 + kc + 2] = (u32)l2 | ((u32)l3 << 16);
    }
    __syncthreads();
    {
      short8 ah[2], al[2], bh[8], bl[8];
      #pragma unroll
      for (int mt = 0; mt < 2; ++mt){
        int rr = (wave * 32 + mt * 16 + l16) * 40 + quad * 8;
        ah[mt] = *(const short8*)&Xh[rr];
        al[mt] = *(const short8*)&Xl[rr];
      }
      #pragma unroll
      for (int nt = 0; nt < 8; ++nt){
        int rr = (nt * 16 + l16) * 40 + quad * 8;
        bh[nt] = *(const short8*)&Wh[rr];
        bl[nt] = *(const short8*)&Wl[rr];
      }
      #pragma unroll
      for (int mt = 0; mt < 2; ++mt)
        #pragma unroll
        for (int nt = 0; nt < 8; ++nt){
          acc[mt][nt] = __builtin_amdgcn_mfma_f32_16x16x32_bf16(ah[mt], bh[nt], acc[mt][nt], 0,0,0);
          acc[mt][nt] = __builtin_amdgcn_mfma_f32_16x16x32_bf16(ah[mt], bl[nt], acc[mt][nt], 0,0,0);
          acc[mt][nt] = __builtin_amdgcn_mfma_f32_16x16x32_bf16(al[mt], bh[nt], acc[mt][nt], 0,0,0);
        }
    }
    __syncthreads();
  }

  // ---- phase-1 epilogue: lrelu+bias -> bf16 tile T in LDS ----
  {
    float bv[8];
    #pragma unroll
    for (int nt = 0; nt < 8; ++nt) bv[nt] = enc_b[a * H_N + nt * 16 + l16];
    #pragma unroll
    for (int mt = 0; mt < 2; ++mt)
      #pragma unroll
      for (int nt = 0; nt < 8; ++nt)
        #pragma unroll
        for (int r = 0; r < 4; ++r){
          int rl = wave * 32 + mt * 16 + quad * 4 + r;
          T[rl * 136 + nt * 16 + l16] = f2bf(lrelu(acc[mt][nt][r] + bv[nt]));
        }
  }
  __syncthreads();
  // vectorized sa_enc store from tile
  for (int c = t; c < 2048; c += 256){
    int row = c >> 4, col8 = (c & 15) * 8;
    *(uint4*)(sa_enc + ((size_t)a * B_N + row0 + row) * H_N + col8) =
        *(const uint4*)&T[row * 136 + col8];
  }

  // ---- phase 2: sels = T @ selT (single-term), BK=32 ----
  #pragma unroll
  for (int mt = 0; mt < 2; ++mt)
    #pragma unroll
    for (int nt = 0; nt < 8; ++nt) acc[mt][nt] = (floatx4){0.f,0.f,0.f,0.f};
  for (int k0 = 0; k0 < H_N; k0 += 32){
    for (int c = t; c < 512; c += 256){
      int n = c >> 2, off = (c & 3) * 8;
      *(uint4*)&Ws[n * 40 + off] = *(const uint4*)(selH + (size_t)n * H_N + k0 + off);
    }
    __syncthreads();
    {
      short8 ah[2], bh[8];
      #pragma unroll
      for (int mt = 0; mt < 2; ++mt)
        ah[mt] = *(const short8*)&T[(wave * 32 + mt * 16 + l16) * 136 + k0 + quad * 8];
      #pragma unroll
      for (int nt = 0; nt < 8; ++nt)
        bh[nt] = *(const short8*)&Ws[(nt * 16 + l16) * 40 + quad * 8];
      #pragma unroll
      for (int mt = 0; mt < 2; ++mt)
        #pragma unroll
        for (int nt = 0; nt < 8; ++nt)
          acc[mt][nt] = __builtin_amdgcn_mfma_f32_16x16x32_bf16(ah[mt], bh[nt], acc[mt][nt], 0,0,0);
    }
    __syncthreads();
  }
  #pragma unroll
  for (int mt = 0; mt < 2; ++mt)
    #pragma unroll
    for (int nt = 0; nt < 8; ++nt)
      #pragma unroll
      for (int r = 0; r < 4; ++r){
        int rl = wave * 32 + mt * 16 + quad * 4 + r;
        T[rl * 136 + nt * 16 + l16] = f2bf(acc[mt][nt][r]);
      }
  __syncthreads();
  for (int c = t; c < 2048; c += 256){
    int row = c >> 4, col8 = (c & 15) * 8;
    *(uint4*)(sels + ((size_t)a * B_N + row0 + row) * H_N + col8) =
        *(const uint4*)&T[row * 136 + col8];
  }
}

// ---------------------------------------------------------------------------
// Fused kernel 2: a_enc = lrelu(BN(actions) @ aenc_w + aenc_b) [3-term, K=32]
//   keys & vals computed in ONE dual-accumulator K-loop (single-term weights).
// a_enc never touches HBM; both outputs stored vectorized.
// ---------------------------------------------------------------------------
__global__ __launch_bounds__(256, 2) void k_aenc_kv(
    const float* __restrict__ actions,
    const float* __restrict__ mean, const float* __restrict__ istd,
    const u16* __restrict__ aencH, const u16* __restrict__ aencL,
    const float* __restrict__ aenc_b,
    const u16* __restrict__ keyH, const u16* __restrict__ valH,
    const float* __restrict__ val_b,
    u16* __restrict__ keys, u16* __restrict__ vals)
{
  int a = blockIdx.y; int row0 = blockIdx.x * 128; int t = threadIdx.x;
  int lane = t & 63, wave = t >> 6, l16 = lane & 15, quad = lane >> 4;
  __shared__ __align__(16) u16 S[35840];
  __shared__ __align__(16) float sc[32], sh[32];
  u16* T  = S;            // [128][136] a_enc tile; later vals tile
  u16* WK = S + 17408;    // [128][72]  key weights (BK=64)
  u16* WV = S + 26624;    // [128][72]  val weights
  u16* T2 = S + 17408;    // [128][136] keys tile (epilogue)

  if (t < 32){
    float m = mean[a * SAF + 128 + t], s = istd[a * SAF + 128 + t];
    sc[t] = s; sh[t] = -m * s;
  }
  floatx4 accK[2][8], accV[2][8];
  #pragma unroll
  for (int mt = 0; mt < 2; ++mt)
    #pragma unroll
    for (int nt = 0; nt < 8; ++nt){
      accK[mt][nt] = (floatx4){0.f,0.f,0.f,0.f};
      accV[mt][nt] = (floatx4){0.f,0.f,0.f,0.f};
    }
  __syncthreads();

  // ---- phase 1: aenc GEMM, K=32 single tile (stride 40) ----
  {
    u16* Wh1 = S;  u16* Wl1 = S + 5120;
    u16* Xh = S + 10240; u16* Xl = S + 15360;
    const u16* wbh = aencH + (size_t)a * H_N * OUT_N;
    const u16* wbl = aencL + (size_t)a * H_N * OUT_N;
    for (int c = t; c < 512; c += 256){
      int n = c >> 2, off = (c & 3) * 8;
      *(uint4*)&Wh1[n * 40 + off] = *(const uint4*)(wbh + (size_t)n * OUT_N + off);
      *(uint4*)&Wl1[n * 40 + off] = *(const uint4*)(wbl + (size_t)n * OUT_N + off);
    }
    for (int c = t; c < 1024; c += 256){
      int r = c >> 3, kc = (c & 7) * 4;
      size_t row = (size_t)a * B_N + row0 + r;
      float4 v = *(const float4*)(actions + row * OUT_N + kc);
      float4 scv = *(const float4*)&sc[kc];
      float4 shv = *(const float4*)&sh[kc];
      float x0 = fmaf(v.x, scv.x, shv.x), x1 = fmaf(v.y, scv.y, shv.y);
      float x2 = fmaf(v.z, scv.z, shv.z), x3 = fmaf(v.w, scv.w, shv.w);
      u16 h0 = f2bf(x0), h1 = f2bf(x1), h2 = f2bf(x2), h3 = f2bf(x3);
      *(u32*)&Xh[r * 40 + kc]     = (u32)h0 | ((u32)h1 << 16);
      *(u32*)&Xh[r * 40 + kc + 2] = (u32)h2 | ((u32)h3 << 16);
      u16 l0 = f2bf(x0 - bf2f(h0)), l1 = f2bf(x1 - bf2f(h1));
      u16 l2 = f2bf(x2 - bf2f(h2)), l3 = f2bf(x3 - bf2f(h3));
      *(u32*)&Xl[r * 40 + kc]     = (u32)l0 | ((u32)l1 << 16);
      *(u32*)&Xl[r * 40 + kc + 2] = (u32)l2 | ((u32)l3 << 16);
    }
    __syncthreads();
    short8 ah[2], al[2], bh[8], bl[8];
    #pragma unroll
    for (int mt = 0; mt < 2; ++mt){
      int rr = (wave * 32 + mt * 16 + l16) * 40 + quad * 8;
      ah[mt] = *(const short8*)&Xh[rr];
      al[mt] = *(const short8*)&Xl[rr];
    }
    #pragma unroll
    for (int nt = 0; nt < 8; ++nt){
      int rr = (nt * 16 + l16) * 40 + quad * 8;
      bh[nt] = *(const short8*)&Wh1[rr];
      bl[nt] = *(const short8*)&Wl1[rr];
    }
    #pragma unroll
    for (int mt = 0; mt < 2; ++mt)
      #pragma unroll
      for (int nt = 0; nt < 8; ++nt){
        accK[mt][nt] = __builtin_amdgcn_mfma_f32_16x16x32_bf16(ah[mt], bh[nt], accK[mt][nt], 0,0,0);
        accK[mt][nt] = __builtin_amdgcn_mfma_f32_16x16x32_bf16(ah[mt], bl[nt], accK[mt][nt], 0,0,0);
        accK[mt][nt] = __builtin_amdgcn_mfma_f32_16x16x32_bf16(al[mt], bh[nt], accK[mt][nt], 0,0,0);
      }
    __syncthreads();
  }
  // a_enc -> LDS tile T; move from accK, then zero accK
  {
    float bv[8];
    #pragma unroll
    for (int nt = 0; nt < 8; ++nt) bv[nt] = aenc_b[a * H_N + nt * 16 + l16];
    #pragma unroll
    for (int mt = 0; mt < 2; ++mt)
      #pragma unroll
      for (int nt = 0; nt < 8; ++nt){
        #pragma unroll
        for (int r = 0; r < 4; ++r){
          int rl = wave * 32 + mt * 16 + quad * 4 + r;
          T[rl * 136 + nt * 16 + l16] = f2bf(lrelu(accK[mt][nt][r] + bv[nt]));
        }
        accK[mt][nt] = (floatx4){0.f,0.f,0.f,0.f};
      }
  }

  // ---- phase 2: keys + vals in one dual-acc loop (BK=64, single-term) ----
  for (int k0 = 0; k0 < H_N; k0 += 64){
    __syncthreads();
    for (int c = t; c < 1024; c += 256){
      int n = c >> 3, off = (c & 7) * 8;
      *(uint4*)&WK[n * 72 + off] = *(const uint4*)(keyH + (size_t)n * H_N + k0 + off);
      *(uint4*)&WV[n * 72 + off] = *(const uint4*)(valH + (size_t)n * H_N + k0 + off);
    }
    __syncthreads();
    #pragma unroll
    for (int ks = 0; ks < 64; ks += 32){
      short8 ah[2], bk[8], bv[8];
      #pragma unroll
      for (int mt = 0; mt < 2; ++mt)
        ah[mt] = *(const short8*)&T[(wave * 32 + mt * 16 + l16) * 136 + k0 + ks + quad * 8];
      #pragma unroll
      for (int nt = 0; nt < 8; ++nt){
        int rr = (nt * 16 + l16) * 72 + ks + quad * 8;
        bk[nt] = *(const short8*)&WK[rr];
        bv[nt] = *(const short8*)&WV[rr];
      }
      #pragma unroll
      for (int mt = 0; mt < 2; ++mt)
        #pragma unroll
        for (int nt = 0; nt < 8; ++nt){
          accK[mt][nt] = __builtin_amdgcn_mfma_f32_16x16x32_bf16(ah[mt], bk[nt], accK[mt][nt], 0,0,0);
          accV[mt][nt] = __builtin_amdgcn_mfma_f32_16x16x32_bf16(ah[mt], bv[nt], accV[mt][nt], 0,0,0);
        }
    }
  }
  __syncthreads();
  // epilogue: vals -> T (with bias+lrelu), keys -> T2; both vectorized
  {
    float bv[8];
    #pragma unroll
    for (int nt = 0; nt < 8; ++nt) bv[nt] = val_b[nt * 16 + l16];
    #pragma unroll
    for (int mt = 0; mt < 2; ++mt)
      #pragma unroll
      for (int nt = 0; nt < 8; ++nt)
        #pragma unroll
        for (int r = 0; r < 4; ++r){
          int rl = wave * 32 + mt * 16 + quad * 4 + r;
          T[rl * 136 + nt * 16 + l16]  = f2bf(lrelu(accV[mt][nt][r] + bv[nt]));
          T2[rl * 136 + nt * 16 + l16] = f2bf(accK[mt][nt][r]);
        }
  }
  __syncthreads();
  for (int c = t; c < 2048; c += 256){
    int row = c >> 4, col8 = (c & 15) * 8;
    *(uint4*)(vals + ((size_t)a * B_N + row0 + row) * H_N + col8) =
        *(const uint4*)&T[row * 136 + col8];
    *(uint4*)(keys + ((size_t)a * B_N + row0 + row) * H_N + col8) =
        *(const uint4*)&T2[row * 136 + col8];
  }
}

// ---------------------------------------------------------------------------
// Attention: block = 8 b-rows, all agents/heads in LDS. `other` may alias
// `keys` (all global reads complete before __syncthreads; rows disjoint
// across blocks).
// ---------------------------------------------------------------------------
__global__ __launch_bounds__(256) void k_attn(
    const u16* __restrict__ sels, const u16* __restrict__ keys,
    const u16* __restrict__ vals, u16* __restrict__ other)
{
  int b0 = blockIdx.x * 8;
  int t = threadIdx.x;
  __shared__ __align__(16) u16 sS[8192], sK[8192], sV[8192];
  u32* dS = (u32*)sS; u32* dK = (u32*)sK; u32* dV = (u32*)sV;
  #pragma unroll
  for (int a = 0; a < 8; ++a){
    size_t go = ((size_t)a * B_N + b0) * KD_N;
    const u32* gs = (const u32*)(sels + go);
    const u32* gk = (const u32*)(keys + go);
    const u32* gv = (const u32*)(vals + go);
    dS[a * 512 + t] = gs[t]; dS[a * 512 + 256 + t] = gs[256 + t];
    dK[a * 512 + t] = gk[t]; dK[a * 512 + 256 + t] = gk[256 + t];
    dV[a * 512 + t] = gv[t]; dV[a * 512 + 256 + t] = gv[256 + t];
  }
  __syncthreads();
  int i = t & 7, p = t >> 3;
  int k = p & 3, bl = p >> 2;
  int base_i = (i * 8 + bl) * 128 + k * 32;
  float si[32];
  {
    const u32* S32 = (const u32*)&sS[base_i];
    #pragma unroll
    for (int d2 = 0; d2 < 16; ++d2){
      u32 u = S32[d2];
      si[2 * d2] = bf_lo(u); si[2 * d2 + 1] = bf_hi(u);
    }
  }
  float lg[8];
  #pragma unroll
  for (int j = 0; j < 8; ++j){
    const u32* K32 = (const u32*)&sK[(j * 8 + bl) * 128 + k * 32];
    float acc = 0.f;
    #pragma unroll
    for (int d2 = 0; d2 < 16; ++d2){
      u32 u = K32[d2];
      acc = fmaf(si[2 * d2], bf_lo(u), acc);
      acc = fmaf(si[2 * d2 + 1], bf_hi(u), acc);
    }
    lg[j] = acc * 0.17677669529663689f;
  }
  float mx = -3.0e38f;
  #pragma unroll
  for (int j = 0; j < 8; ++j) if (j != i) mx = fmaxf(mx, lg[j]);
  float pe[8], se = 0.f;
  #pragma unroll
  for (int j = 0; j < 8; ++j){
    pe[j] = (j == i) ? 0.f : __expf(lg[j] - mx);
    se += pe[j];
  }
  float inv = 1.f / se;
  #pragma unroll
  for (int j = 0; j < 8; ++j) pe[j] *= inv;
  __align__(16) u16 ob[32];
  #pragma unroll
  for (int d2 = 0; d2 < 16; ++d2){
    float acc0 = 0.f, acc1 = 0.f;
    #pragma unroll
    for (int j = 0; j < 8; ++j){
      u32 u = *(const u32*)&sV[(j * 8 + bl) * 128 + k * 32 + 2 * d2];
      acc0 = fmaf(pe[j], bf_lo(u), acc0);
      acc1 = fmaf(pe[j], bf_hi(u), acc1);
    }
    ob[2 * d2] = f2bf(acc0); ob[2 * d2 + 1] = f2bf(acc1);
  }
  uint4* dst = (uint4*)(other + ((size_t)i * B_N + (b0 + bl)) * KD_N + k * 32);
  const uint4* s4 = (const uint4*)ob;
  #pragma unroll
  for (int c = 0; c < 4; ++c) dst[c] = s4[c];
}

// ---------------------------------------------------------------------------
// Critic: h = lrelu([sa_enc|other] @ c1_w + c1_b); q = h . c2_w + c2_b
// 2-term hi/lo, K=256, BK=32. LDS 30720 B -> high occupancy.
// ---------------------------------------------------------------------------
__global__ __launch_bounds__(256, 3) void k_critic(
    const u16* __restrict__ sa_enc, const u16* __restrict__ other,
    const u16* __restrict__ c1H, const u16* __restrict__ c1L,
    const float* __restrict__ c1_b,
    const float* __restrict__ c2w, const float* __restrict__ c2b,
    float* __restrict__ qout)
{
  int a = blockIdx.y; int row0 = blockIdx.x * 128; int t = threadIdx.x;
  int lane = t & 63, wave = t >> 6, l16 = lane & 15, quad = lane >> 4;
  __shared__ __align__(16) u16 Xs[5120];
  __shared__ __align__(16) u16 Wh[5120];
  __shared__ __align__(16) u16 Wl[5120];
  floatx4 acc[2][8];
  #pragma unroll
  for (int mt = 0; mt < 2; ++mt)
    #pragma unroll
    for (int nt = 0; nt < 8; ++nt) acc[mt][nt] = (floatx4){0.f,0.f,0.f,0.f};
  const u16* wbh = c1H + (size_t)a * H_N * CIN_N;
  const u16* wbl = c1L + (size_t)a * H_N * CIN_N;

  for (int k0 = 0; k0 < CIN_N; k0 += 32){
    for (int c = t; c < 512; c += 256){
      int n = c >> 2, off = (c & 3) * 8;
      *(uint4*)&Wh[n * 40 + off] = *(const uint4*)(wbh + (size_t)n * CIN_N + k0 + off);
      *(uint4*)&Wl[n * 40 + off] = *(const uint4*)(wbl + (size_t)n * CIN_N + k0 + off);
    }
    for (int c = t; c < 512; c += 256){
      int r = c >> 2, off = (c & 3) * 8;
      int fo = k0 + off;
      const u16* src = sa_enc;
      if (fo >= H_N){ src = other; fo -= H_N; }
      *(uint4*)&Xs[r * 40 + off] =
          *(const uint4*)(src + ((size_t)a * B_N + row0 + r) * H_N + fo);
    }
    __syncthreads();
    {
      short8 ah[2], bh[8], bl[8];
      #pragma unroll
      for (int mt = 0; mt < 2; ++mt)
        ah[mt] = *(const short8*)&Xs[(wave * 32 + mt * 16 + l16) * 40 + quad * 8];
      #pragma unroll
      for (int nt = 0; nt < 8; ++nt){
        int rr = (nt * 16 + l16) * 40 + quad * 8;
        bh[nt] = *(const short8*)&Wh[rr];
        bl[nt] = *(const short8*)&Wl[rr];
      }
      #pragma unroll
      for (int mt = 0; mt < 2; ++mt)
        #pragma unroll
        for (int nt = 0; nt < 8; ++nt){
          acc[mt][nt] = __builtin_amdgcn_mfma_f32_16x16x32_bf16(ah[mt], bh[nt], acc[mt][nt], 0,0,0);
          acc[mt][nt] = __builtin_amdgcn_mfma_f32_16x16x32_bf16(ah[mt], bl[nt], acc[mt][nt], 0,0,0);
        }
    }
    __syncthreads();
  }

  float c2r[8], bv[8];
  #pragma unroll
  for (int nt = 0; nt < 8; ++nt){
    c2r[nt] = c2w[a * H_N + nt * 16 + l16];
    bv[nt]  = c1_b[a * H_N + nt * 16 + l16];
  }
  #pragma unroll
  for (int mt = 0; mt < 2; ++mt){
    #pragma unroll
    for (int r = 0; r < 4; ++r){
      float s = 0.f;
      #pragma unroll
      for (int nt = 0; nt < 8; ++nt){
        float h = lrelu(acc[mt][nt][r] + bv[nt]);
        s = fmaf(h, c2r[nt], s);
      }
      s += __shfl_xor(s, 1);
      s += __shfl_xor(s, 2);
      s += __shfl_xor(s, 4);
      s += __shfl_xor(s, 8);
      if (l16 == 0){
        int row = row0 + wave * 32 + mt * 16 + quad * 4 + r;
        qout[(size_t)a * B_N + row] = s + c2b[a];
      }
    }
  }
}

// ---------------------------------------------------------------------------
extern "C" void kernel_launch(void* const* d_in, const int* in_sizes, int n_in,
                              void* d_out, int out_size, void* d_ws, size_t ws_size,
                              hipStream_t stream)
{
  const float* states  = (const float*)d_in[0];
  const float* actions = (const float*)d_in[1];
  const float* enc_w   = (const float*)d_in[2];
  const float* enc_b   = (const float*)d_in[3];
  const float* aenc_w  = (const float*)d_in[4];
  const float* aenc_b  = (const float*)d_in[5];
  const float* key_w   = (const float*)d_in[6];
  const float* sel_w   = (const float*)d_in[7];
  const float* val_w   = (const float*)d_in[8];
  const float* val_b   = (const float*)d_in[9];
  const float* c1_w    = (const float*)d_in[10];
  const float* c1_b    = (const float*)d_in[11];
  const float* c2_w    = (const float*)d_in[12];
  const float* c2_b    = (const float*)d_in[13];
  float* q = (float*)d_out;

  char* ws = (char*)d_ws;
  // Pack region [0, 1,015,808) overlaps stats partials [0, 1,310,720):
  // stats/finalize consume `part` before k_pack overwrites (sequential stream).
  u16* encH  = (u16*)(ws + 0);          // 393216 B
  u16* encL  = (u16*)(ws + 393216);     // 393216 B
  u16* aencH = (u16*)(ws + 786432);     //  65536 B
  u16* aencL = (u16*)(ws + 851968);     //  65536 B
  u16* keyH  = (u16*)(ws + 917504);     //  32768 B
  u16* selH  = (u16*)(ws + 950272);     //  32768 B
  u16* valH  = (u16*)(ws + 983040);     //  32768 B -> ends 1,015,808
  float* part    = (float*)ws;          // 1,310,720 B (dead after finalize)
  float* meanArr = (float*)(ws + 1310720);
  float* istdArr = (float*)(ws + 1315840);
  u16* c1H = (u16*)(ws + 1320960);      // 524288 B
  u16* c1L = (u16*)(ws + 1845248);      // 524288 B -> ends 2,369,536
  const size_t ibase = 4194304;
  const size_t BUF = (size_t)A_N * B_N * 128 * 2;   // 64 MB
  u16* sa_enc = (u16*)(ws + ibase);
  u16* sels   = (u16*)(ws + ibase + BUF);
  u16* keys   = (u16*)(ws + ibase + 2 * BUF);       // keys, later `other`
  u16* vals   = (u16*)(ws + ibase + 3 * BUF);

  k_stats<<<dim3(CHUNKS, A_N), 256, 0, stream>>>(states, actions, part);
  k_finalize<<<(A_N * SAF + 255) / 256, 256, 0, stream>>>(part, meanArr, istdArr);
  k_pack<<<(PACK_TOTAL + 255) / 256, 256, 0, stream>>>(
      enc_w, aenc_w, key_w, sel_w, val_w, c1_w,
      encH, encL, aencH, aencL, keyH, selH, valH, c1H, c1L);

  dim3 g(B_N / 128, A_N);
  k_enc_sel<<<g, 256, 0, stream>>>(states, actions, meanArr, istdArr,
                                   encH, encL, enc_b, selH, sa_enc, sels);
  k_aenc_kv<<<g, 256, 0, stream>>>(actions, meanArr, istdArr,
                                   aencH, aencL, aenc_b, keyH, valH, val_b,
                                   keys, vals);
  k_attn<<<B_N / 8, 256, 0, stream>>>(sels, keys, vals, keys);  // other -> keys
  k_critic<<<g, 256, 0, stream>>>(sa_enc, keys, c1H, c1L, c1_b, c2_w, c2_b, q);
}